// Round 3
// baseline (3600.570 us; speedup 1.0000x reference)
//
#include <hip/hip_runtime.h>

// ---------------- problem constants ----------------
#define Nq   4096
#define DHq  64
#define Mq   256
#define BHq  32

using bf16 = __bf16;
using bf16x8 = __bf16 __attribute__((ext_vector_type(8)));
using bf16x4 = __bf16 __attribute__((ext_vector_type(4)));
using f32x4 = float __attribute__((ext_vector_type(4)));

__device__ __forceinline__ f32x4 mfma16(bf16x8 a, bf16x8 b, f32x4 c) {
  return __builtin_amdgcn_mfma_f32_16x16x32_bf16(a, b, c, 0, 0, 0);
}
__device__ __forceinline__ unsigned short f2bu(float f) {
  bf16 b = (bf16)f;
  return __builtin_bit_cast(unsigned short, b);
}
__device__ __forceinline__ void split_store(bf16* h, bf16* l, long idx, float v) {
  bf16 hi = (bf16)v;
  h[idx] = hi;
  l[idx] = (bf16)(v - (float)hi);
}

// Stage a ROWS x 32 bf16 tile into LDS, row stride 40 bf16 (80 B).
// SRC: 0 = bf16 row-major, 1 = f32 row-major, 3 = bf16 gather from oh[bh][4096][64]
template<int ROWS, int SRC>
__device__ __forceinline__ void stageA(const void* src, long ld, long row0, int k0,
                                       bf16* dst, int t) {
#pragma unroll
  for (int c = 0; c < ROWS / 64; ++c) {
    int idx = t + 256 * c;
    int r = idx >> 2;
    int kc = (idx & 3) << 3;
    bf16x8 val;
    if constexpr (SRC == 0) {
      val = *(const bf16x8*)((const bf16*)src + (row0 + r) * ld + k0 + kc);
    } else if constexpr (SRC == 1) {
      const float* s = (const float*)src + (row0 + r) * ld + k0 + kc;
      float4 a = *(const float4*)s;
      float4 b = *(const float4*)(s + 4);
      val[0]=(bf16)a.x; val[1]=(bf16)a.y; val[2]=(bf16)a.z; val[3]=(bf16)a.w;
      val[4]=(bf16)b.x; val[5]=(bf16)b.y; val[6]=(bf16)b.z; val[7]=(bf16)b.w;
    } else {
      long m = row0 + r;
      long bb = m >> 12, ii = m & 4095;
      int k = k0 + kc;
      long h = k >> 6, d = k & 63;
      val = *(const bf16x8*)((const bf16*)src + (((bb * 8 + h) * 4096 + ii) * 64 + d));
    }
    *(bf16x8*)(dst + r * 40 + kc) = val;
  }
}

// Stage 32 x COLS tile of row-major [K][N] B into word-LDS [COLS][20 words].
template<int COLS, bool F32>
__device__ __forceinline__ void stageBN(const void* src, long ld, long n0, int k0,
                                        unsigned int* dst, int t) {
  int kp = t >> 4;
  int nb = (t & 15) << 2;
#pragma unroll
  for (int g = 0; g < COLS / 64; ++g) {
    int n = nb + (g << 6);
    unsigned int w0, w1, w2, w3;
    if constexpr (F32) {
      const float* s0 = (const float*)src + (long)(k0 + 2 * kp) * ld + n0 + n;
      const float* s1 = s0 + ld;
      float4 a = *(const float4*)s0;
      float4 b = *(const float4*)s1;
      w0 = f2bu(a.x) | ((unsigned)f2bu(b.x) << 16);
      w1 = f2bu(a.y) | ((unsigned)f2bu(b.y) << 16);
      w2 = f2bu(a.z) | ((unsigned)f2bu(b.z) << 16);
      w3 = f2bu(a.w) | ((unsigned)f2bu(b.w) << 16);
    } else {
      const unsigned short* s0 = (const unsigned short*)src + (long)(k0 + 2 * kp) * ld + n0 + n;
      const unsigned short* s1 = s0 + ld;
      ushort4 a = *(const ushort4*)s0;
      ushort4 b = *(const ushort4*)s1;
      w0 = a.x | ((unsigned)b.x << 16);
      w1 = a.y | ((unsigned)b.y << 16);
      w2 = a.z | ((unsigned)b.z << 16);
      w3 = a.w | ((unsigned)b.w << 16);
    }
    dst[(n + 0) * 20 + kp] = w0;
    dst[(n + 1) * 20 + kp] = w1;
    dst[(n + 2) * 20 + kp] = w2;
    dst[(n + 3) * 20 + kp] = w3;
  }
}

#define EQKV 0
#define EA2 1
#define EY 4
#define EG2 5
#define EG3 6
#define EG4 7
#define EWT 8
#define EBIAS 9

struct GP {
  const void* A; const void* Al;
  const void* B; const void* Bl;
  long ldA, ldB, sA, sB;
  int K;
  void* C0; void* C1; void* C2;
  long sC, ldC;
  const void* x0; const void* x1;
  const float* bias;
};

template<int BM, int BN, int WX, int ASRC, int BMODE, int SPLIT, int EPI>
__device__ void gphase(const GP& p, long bz, long m0, long n0, int t, char* Lbuf) {
  constexpr int WY = 4 / WX;
  constexpr int TM = BM / WY, TN = BN / WX;
  constexpr int IT = TM / 16, JT = TN / 16;
  constexpr int AB = (SPLIT ? 2 : 1) * BM * 80;
  bf16* AsL = (bf16*)Lbuf;
  unsigned int* BsL = (unsigned int*)(Lbuf + AB);
  int wv = t >> 6, lane = t & 63;
  int wy = wv / WX, wx = wv % WX;
  int qd = lane >> 4, lm = lane & 15;

  const void* Ap; const void* Alp = nullptr;
  if constexpr (ASRC == 0) Ap = (const bf16*)p.A + bz * p.sA;
  else Ap = p.A;
  if constexpr (SPLIT) Alp = (const bf16*)p.Al + bz * p.sA;
  const void* Bp; const void* Blp = nullptr;
  if constexpr (BMODE == 2) Bp = p.B;
  else Bp = (const bf16*)p.B + bz * p.sB;
  if constexpr (SPLIT) Blp = (const bf16*)p.Bl + bz * p.sB;

  f32x4 acc[IT][JT];
#pragma unroll
  for (int i = 0; i < IT; ++i)
#pragma unroll
    for (int j = 0; j < JT; ++j) acc[i][j] = (f32x4)0.0f;

  for (int k0 = 0; k0 < p.K; k0 += 32) {
    stageA<BM, ASRC>(Ap, p.ldA, m0, k0, AsL, t);
    if constexpr (SPLIT) stageA<BM, 0>(Alp, p.ldA, m0, k0, AsL + BM * 40, t);
    if constexpr (BMODE == 0) {
      stageA<BN, 0>(Bp, p.ldB, n0, k0, (bf16*)BsL, t);
      if constexpr (SPLIT) stageA<BN, 0>(Blp, p.ldB, n0, k0, (bf16*)BsL + BN * 40, t);
    } else {
      stageBN<BN, BMODE == 2>(Bp, p.ldB, n0, k0, BsL, t);
      if constexpr (SPLIT) stageBN<BN, false>(Blp, p.ldB, n0, k0, BsL + BN * 20, t);
    }
    __syncthreads();
    bf16x8 af[IT], afl[IT];
#pragma unroll
    for (int i = 0; i < IT; ++i) {
      int m = wy * TM + i * 16 + lm;
      af[i] = *(const bf16x8*)(AsL + m * 40 + qd * 8);
      if constexpr (SPLIT) afl[i] = *(const bf16x8*)(AsL + BM * 40 + m * 40 + qd * 8);
    }
#pragma unroll
    for (int j = 0; j < JT; ++j) {
      int n = wx * TN + j * 16 + lm;
      bf16x8 bf, bfl;
      if constexpr (BMODE == 0) {
        bf = *(const bf16x8*)((const bf16*)BsL + n * 40 + qd * 8);
        if constexpr (SPLIT) bfl = *(const bf16x8*)((const bf16*)BsL + BN * 40 + n * 40 + qd * 8);
      } else {
        bf = *(const bf16x8*)((const bf16*)(BsL + n * 20 + qd * 4));
        if constexpr (SPLIT) bfl = *(const bf16x8*)((const bf16*)(BsL + BN * 20 + n * 20 + qd * 4));
      }
#pragma unroll
      for (int i = 0; i < IT; ++i) {
        acc[i][j] = mfma16(af[i], bf, acc[i][j]);
        if constexpr (SPLIT) {
          acc[i][j] = mfma16(af[i], bfl, acc[i][j]);
          acc[i][j] = mfma16(afl[i], bf, acc[i][j]);
        }
      }
    }
    __syncthreads();
  }

  if constexpr (EPI == EA2) {
#pragma unroll
    for (int r = 0; r < 4; ++r) {
      long row = m0 + wy * TM + qd * 4 + r;
      float e[JT];
      float s = 0.f;
#pragma unroll
      for (int j = 0; j < JT; ++j) { e[j] = __expf(acc[0][j][r]); s += e[j]; }
      s += __shfl_xor(s, 1); s += __shfl_xor(s, 2);
      s += __shfl_xor(s, 4); s += __shfl_xor(s, 8);
      float inv = 1.0f / s;
#pragma unroll
      for (int j = 0; j < JT; ++j) {
        long col = n0 + j * 16 + lm;
        split_store((bf16*)p.C0, (bf16*)p.C1, bz * p.sC + row * p.ldC + col, e[j] * inv);
      }
    }
  } else {
#pragma unroll
    for (int i = 0; i < IT; ++i)
#pragma unroll
      for (int j = 0; j < JT; ++j)
#pragma unroll
        for (int r = 0; r < 4; ++r) {
          long row = m0 + wy * TM + i * 16 + qd * 4 + r;
          long col = n0 + wx * TN + j * 16 + lm;
          float v = acc[i][j][r];
          if constexpr (EPI == EQKV) {
            int part = (int)(col >> 9);
            long h = (col >> 6) & 7, d = col & 63;
            long bb = row >> 12, ii = row & 4095;
            float scv = part == 0 ? 0.125f : 1.0f;
            bf16* dst = part == 0 ? (bf16*)p.C0 : (part == 1 ? (bf16*)p.C1 : (bf16*)p.C2);
            dst[((bb * 8 + h) * 4096 + ii) * 64 + d] = (bf16)(v * scv);
          } else if constexpr (EPI == EY) {
            split_store((bf16*)p.C0, (bf16*)p.C1, bz * 65536 + row * 256 + col, v);
          } else if constexpr (EPI == EG2) {
            long ix = bz * 65536 + row * 256 + col;
            float y = (float)((const bf16*)p.x0)[ix] + (float)((const bf16*)p.x1)[ix];
            float val = (row == col ? 15.0f : 0.0f) - 7.0f * y + v;
            split_store((bf16*)p.C0, (bf16*)p.C1, ix, val);
          } else if constexpr (EPI == EG3) {
            float val = (row == col ? 13.0f : 0.0f) - v;
            split_store((bf16*)p.C0, (bf16*)p.C1, bz * 65536 + row * 256 + col, val);
          } else if constexpr (EPI == EG4) {
            split_store((bf16*)p.C0, (bf16*)p.C1, bz * 65536 + row * 256 + col, 0.25f * v);
          } else if constexpr (EPI == EWT) {
            ((bf16*)p.C0)[bz * 16384 + col * 256 + row] = (bf16)v;
          } else if constexpr (EPI == EBIAS) {
            ((float*)p.C0)[row * 512 + col] = v + p.bias[col];
          }
        }
  }
}

template<int BM, int BN, int WX, int ASRC, int BMODE, int SPLIT, int EPI>
__global__ __launch_bounds__(256, 2) void mgemm(GP p) {
  constexpr int AB = (SPLIT ? 2 : 1) * BM * 80;
  constexpr int BB = (SPLIT ? 2 : 1) * BN * 80;
  __shared__ __align__(16) char L[AB + BB];
  gphase<BM, BN, WX, ASRC, BMODE, SPLIT, EPI>(
      p, blockIdx.z, (long)blockIdx.y * BM, (long)blockIdx.x * BN, threadIdx.x, L);
}

// ---------------- grid barrier ----------------
__device__ __forceinline__ void gbar(unsigned int* cnt, unsigned int goal, int t) {
  __syncthreads();
  if (t == 0) {
    __threadfence();
    __hip_atomic_fetch_add(cnt, 1u, __ATOMIC_ACQ_REL, __HIP_MEMORY_SCOPE_AGENT);
    while (__hip_atomic_load(cnt, __ATOMIC_ACQUIRE, __HIP_MEMORY_SCOPE_AGENT) < goal)
      __builtin_amdgcn_s_sleep(2);
  }
  __syncthreads();
  __threadfence();
}

// ---------------- mega kernel: attn2, colsum, zinit, a3v, norm, pinv x24, Wt ----
struct MegaP {
  const bf16 *qlh, *qll, *klh, *kll, *kb, *vb;
  bf16 *A2h, *A2l, *zAh, *zAl, *zBh, *zBl;
  bf16 *yh, *yl, *bbh, *bbl, *cch, *ccl;
  float *a3vf, *rs3;
  unsigned int *sc, *cnt;
  bf16 *a3vh, *a3vl, *Wt;
};

__device__ void a3v_body(const MegaP& mp, int b, int t, char* L) {
  long bz = b >> 4;
  int qt = (b >> 2) & 3, kt = b & 3;
  bf16* qlS = (bf16*)L;                     // [64][72]
  bf16* kS  = (bf16*)(L + 9216);            // [64][72]
  bf16* PA  = (bf16*)(L + 18432);           // [64][72]
  unsigned int* vB0 = (unsigned int*)(L + 27648);  // [64][20]
  unsigned int* vB1 = (unsigned int*)(L + 32768);  // [64][20]
  float* rsL = (float*)(L + 37888);         // [64][2]
  int wv = t >> 6, lane = t & 63, qd = lane >> 4, lm = lane & 15;
  int wy = wv >> 1, wx = wv & 1;
  const bf16* qlp = mp.qlh + bz * 16384 + qt * 64 * 64;
#pragma unroll
  for (int c = 0; c < 2; ++c) {
    int idx = t + 256 * c;
    int r = idx >> 3, dc = (idx & 7) * 8;
    *(bf16x8*)(qlS + r * 72 + dc) = *(const bf16x8*)(qlp + r * 64 + dc);
  }
  const bf16* kb_ = mp.kb + bz * 262144 + (long)kt * 65536;
  const bf16* vb_ = mp.vb + bz * 262144 + (long)kt * 65536;
  f32x4 accO[2][2];
  float rsum[2][4];
#pragma unroll
  for (int i = 0; i < 2; ++i) {
#pragma unroll
    for (int j = 0; j < 2; ++j) accO[i][j] = (f32x4)0.0f;
#pragma unroll
    for (int r = 0; r < 4; ++r) rsum[i][r] = 0.f;
  }
  for (int tt = 0; tt < 16; ++tt) {
    __syncthreads();
    const bf16* ks_ = kb_ + tt * 4096;
#pragma unroll
    for (int c = 0; c < 2; ++c) {
      int idx = t + 256 * c;
      int r = idx >> 3, dc = (idx & 7) * 8;
      *(bf16x8*)(kS + r * 72 + dc) = *(const bf16x8*)(ks_ + r * 64 + dc);
    }
    const bf16* vs_ = vb_ + tt * 4096;
    stageBN<64, false>(vs_, 64, 0, 0, vB0, t);
    stageBN<64, false>(vs_, 64, 0, 32, vB1, t);
    __syncthreads();
    f32x4 s[2][2];
#pragma unroll
    for (int i = 0; i < 2; ++i)
#pragma unroll
      for (int j = 0; j < 2; ++j) s[i][j] = (f32x4)0.0f;
#pragma unroll
    for (int ks = 0; ks < 2; ++ks) {
      bf16x8 af[2], bfv[2];
#pragma unroll
      for (int i = 0; i < 2; ++i)
        af[i] = *(const bf16x8*)(qlS + (wy * 32 + i * 16 + lm) * 72 + ks * 32 + qd * 8);
#pragma unroll
      for (int j = 0; j < 2; ++j)
        bfv[j] = *(const bf16x8*)(kS + (wx * 32 + j * 16 + lm) * 72 + ks * 32 + qd * 8);
#pragma unroll
      for (int i = 0; i < 2; ++i)
#pragma unroll
        for (int j = 0; j < 2; ++j) s[i][j] = mfma16(af[i], bfv[j], s[i][j]);
    }
#pragma unroll
    for (int i = 0; i < 2; ++i)
#pragma unroll
      for (int r = 0; r < 4; ++r) {
        float e0 = __expf(s[i][0][r]);
        float e1 = __expf(s[i][1][r]);
        int row = wy * 32 + i * 16 + qd * 4 + r;
        PA[row * 72 + wx * 32 + 0 * 16 + lm] = (bf16)e0;
        PA[row * 72 + wx * 32 + 1 * 16 + lm] = (bf16)e1;
        float cs = e0 + e1;
        cs += __shfl_xor(cs, 1); cs += __shfl_xor(cs, 2);
        cs += __shfl_xor(cs, 4); cs += __shfl_xor(cs, 8);
        rsum[i][r] += cs;
      }
    __syncthreads();
#pragma unroll
    for (int ks = 0; ks < 2; ++ks) {
      unsigned int* vB = ks ? vB1 : vB0;
      bf16x8 af[2], bfv[2];
#pragma unroll
      for (int i = 0; i < 2; ++i)
        af[i] = *(const bf16x8*)(PA + (wy * 32 + i * 16 + lm) * 72 + ks * 32 + qd * 8);
#pragma unroll
      for (int j = 0; j < 2; ++j)
        bfv[j] = *(const bf16x8*)((const bf16*)(vB + (wx * 32 + j * 16 + lm) * 20) + qd * 8);
#pragma unroll
      for (int i = 0; i < 2; ++i)
#pragma unroll
        for (int j = 0; j < 2; ++j) accO[i][j] = mfma16(af[i], bfv[j], accO[i][j]);
    }
  }
  if (lm == 0) {
#pragma unroll
    for (int i = 0; i < 2; ++i)
#pragma unroll
      for (int r = 0; r < 4; ++r)
        rsL[(wy * 32 + i * 16 + qd * 4 + r) * 2 + wx] = rsum[i][r];
  }
  __syncthreads();
  if (t < 64) atomicAdd(&mp.rs3[bz * 256 + qt * 64 + t], rsL[t * 2] + rsL[t * 2 + 1]);
#pragma unroll
  for (int i = 0; i < 2; ++i)
#pragma unroll
    for (int j = 0; j < 2; ++j)
#pragma unroll
      for (int r = 0; r < 4; ++r) {
        long row = bz * 256 + qt * 64 + wy * 32 + i * 16 + qd * 4 + r;
        long col = wx * 32 + j * 16 + lm;
        atomicAdd(&mp.a3vf[row * 64 + col], accO[i][j][r]);
      }
}

__global__ __launch_bounds__(256, 2) void k_mega(MegaP mp) {
  __shared__ __align__(16) char L[51200];
  int t = threadIdx.x;
  int b = blockIdx.x;  // 0..511
  unsigned int goal = 0;
#define NEXTP() do { goal += 512; gbar(mp.cnt, goal, t); } while (0)

  // p0: attn2 = softmax(ql @ kl^T), split
  if (b < 128) {
    GP p{};
    p.A = mp.qlh; p.Al = mp.qll; p.ldA = 64; p.sA = 16384;
    p.B = mp.klh; p.Bl = mp.kll; p.ldB = 64; p.sB = 16384; p.K = 64;
    p.C0 = mp.A2h; p.C1 = mp.A2l; p.sC = 65536; p.ldC = 256;
    gphase<64, 256, 1, 0, 0, 1, EA2>(p, b >> 2, (long)(b & 3) * 64, 0, t, L);
  }
  NEXTP();
  // p1: colsum -> sc (global max of column sums)
  if (b < 32) {
    const bf16* ph = mp.A2h + (long)b * 65536 + t;
    const bf16* pl = mp.A2l + (long)b * 65536 + t;
    float s = 0.f;
    for (int i = 0; i < 256; ++i) s += (float)ph[i * 256] + (float)pl[i * 256];
    float* red = (float*)L;
    red[t] = s; __syncthreads();
    for (int o = 128; o > 0; o >>= 1) {
      if (t < o) red[t] = fmaxf(red[t], red[t + o]);
      __syncthreads();
    }
    if (t == 0) atomicMax(mp.sc, __float_as_uint(red[0]));
  }
  NEXTP();
  // p2: zinit z0 = A2^T / sc
  {
    int bh = b >> 4, ti = (b >> 2) & 3, tj = b & 3;
    float (*T)[65] = (float (*)[65])L;
    int c = t & 63, r0 = t >> 6;
    long base = (long)bh * 65536;
    float inv = 1.0f / __uint_as_float(mp.sc[0]);
#pragma unroll
    for (int rr = 0; rr < 16; ++rr) {
      int r = r0 * 16 + rr;
      long idx = base + (long)(ti * 64 + r) * 256 + tj * 64 + c;
      T[r][c] = (float)mp.A2h[idx] + (float)mp.A2l[idx];
    }
    __syncthreads();
#pragma unroll
    for (int rr = 0; rr < 16; ++rr) {
      int jl = r0 * 16 + rr;
      float v = T[c][jl] * inv;
      long o = base + (long)(tj * 64 + jl) * 256 + ti * 64 + c;
      split_store(mp.zAh, mp.zAl, o, v);
    }
  }
  NEXTP();
  // p3: a3v partial accumulation (flash-style, no P3 materialization)
  a3v_body(mp, b, t, L);
  NEXTP();
  // p4: a3v normalize + split
  {
    long e0 = (long)b * 1024 + t * 4;
    float4 vv = *(const float4*)&mp.a3vf[e0];
    float inv = 1.0f / mp.rs3[e0 >> 6];
    split_store(mp.a3vh, mp.a3vl, e0 + 0, vv.x * inv);
    split_store(mp.a3vh, mp.a3vl, e0 + 1, vv.y * inv);
    split_store(mp.a3vh, mp.a3vl, e0 + 2, vv.z * inv);
    split_store(mp.a3vh, mp.a3vl, e0 + 3, vv.w * inv);
  }
  NEXTP();
  // p5..p28: Newton-Schulz pinv, split-bf16, 4 phases x 6 iters
  {
    long bz = b >> 4;
    long m0 = (long)((b >> 2) & 3) * 64, n0 = (long)(b & 3) * 64;
    for (int it = 0; it < 6; ++it) {
      const bf16* zh = (it & 1) ? mp.zBh : mp.zAh;
      const bf16* zl = (it & 1) ? mp.zBl : mp.zAl;
      bf16* znh = (it & 1) ? mp.zAh : mp.zBh;
      bf16* znl = (it & 1) ? mp.zAl : mp.zBl;
      GP p{};
      p.ldA = 256; p.sA = 65536; p.ldB = 256; p.sB = 65536; p.K = 256;
      p.A = mp.A2h; p.Al = mp.A2l; p.B = zh; p.Bl = zl;
      p.C0 = mp.yh; p.C1 = mp.yl;
      gphase<64, 64, 2, 0, 1, 1, EY>(p, bz, m0, n0, t, L);
      NEXTP();
      p.A = mp.yh; p.Al = mp.yl; p.B = mp.yh; p.Bl = mp.yl;
      p.C0 = mp.bbh; p.C1 = mp.bbl; p.x0 = mp.yh; p.x1 = mp.yl;
      gphase<64, 64, 2, 0, 1, 1, EG2>(p, bz, m0, n0, t, L);
      NEXTP();
      p.A = mp.yh; p.Al = mp.yl; p.B = mp.bbh; p.Bl = mp.bbl;
      p.C0 = mp.cch; p.C1 = mp.ccl;
      gphase<64, 64, 2, 0, 1, 1, EG3>(p, bz, m0, n0, t, L);
      NEXTP();
      p.A = zh; p.Al = zl; p.B = mp.cch; p.Bl = mp.ccl;
      p.C0 = znh; p.C1 = znl;
      gphase<64, 64, 2, 0, 1, 1, EG4>(p, bz, m0, n0, t, L);
      NEXTP();
    }
  }
  // p29: Wt = (z @ a3v)^T   (z = zA after 6 iters)
  if (b < 128) {
    GP p{};
    p.A = mp.zAh; p.Al = mp.zAl; p.ldA = 256; p.sA = 65536;
    p.B = mp.a3vh; p.Bl = mp.a3vl; p.ldB = 64; p.sB = 16384; p.K = 256;
    p.C0 = mp.Wt;
    gphase<64, 64, 2, 0, 1, 1, EWT>(p, b >> 2, (long)(b & 3) * 64, 0, t, L);
  }
#undef NEXTP
}

// ---------------- small kernels ----------------
__global__ void k_zero(float* a3vf, float* rs3, unsigned int* sc, unsigned int* cnt) {
  long i = (long)blockIdx.x * 256 + threadIdx.x;
  a3vf[i] = 0.f;
  if (i < 8192) rs3[i] = 0.f;
  if (i == 0) { sc[0] = 0u; cnt[0] = 0u; }
}

__global__ void k_landmarks(const bf16* q, const bf16* k, bf16* qlh, bf16* qll,
                            bf16* klh, bf16* kll) {
  int bm = blockIdx.x;
  int bh = bm >> 8, mi = bm & 255;
  int d = threadIdx.x;
  const bf16* qp = q + ((long)bh * 4096 + mi * 16) * 64 + d;
  const bf16* kp = k + ((long)bh * 4096 + mi * 16) * 64 + d;
  float sq = 0.f, sk = 0.f;
#pragma unroll
  for (int tt = 0; tt < 16; ++tt) { sq += (float)qp[tt * 64]; sk += (float)kp[tt * 64]; }
  sq *= 0.0625f; sk *= 0.0625f;
  long o = (long)bh * 16384 + mi * 64 + d;
  split_store(qlh, qll, o, sq);
  split_store(klh, kll, o, sk);
}

// fused: oh = softmax(q @ kl^T) @ W  (bf16 out), Wt [bh][64][256]
__global__ __launch_bounds__(256, 2) void k_attn1w(const bf16* qb, const bf16* klb,
                                                   const bf16* Wt, bf16* oh) {
  __shared__ __align__(16) char L[38912];
  bf16* Aq = (bf16*)L;             // [64][40]
  bf16* Bkl = (bf16*)(L + 5120);   // [256][40]
  bf16* Pl = (bf16*)L;             // [64][264] (reuse after stage-1)
  bf16* Bw = (bf16*)(L + 33792);   // [64][40]
  int t = threadIdx.x, wv = t >> 6, lane = t & 63;
  int qd = lane >> 4, lm = lane & 15;
  long bz = blockIdx.z;
  long m0 = (long)blockIdx.x * 64;
  const bf16* qA = qb + bz * (4096L * 64);
  const bf16* klA = klb + bz * (256L * 64);
  const bf16* WtA = Wt + bz * 16384;

  f32x4 a1[16];
#pragma unroll
  for (int j = 0; j < 16; ++j) a1[j] = (f32x4)0.0f;
  for (int k0 = 0; k0 < 64; k0 += 32) {
    stageA<64, 0>(qA, 64, m0, k0, Aq, t);
    stageA<256, 0>(klA, 64, 0, k0, Bkl, t);
    __syncthreads();
    bf16x8 af = *(const bf16x8*)(Aq + (wv * 16 + lm) * 40 + qd * 8);
#pragma unroll
    for (int j = 0; j < 16; ++j) {
      bf16x8 bf = *(const bf16x8*)(Bkl + (j * 16 + lm) * 40 + qd * 8);
      a1[j] = mfma16(af, bf, a1[j]);
    }
    __syncthreads();
  }
  float rs[4];
#pragma unroll
  for (int r = 0; r < 4; ++r) {
    int rowl = wv * 16 + qd * 4 + r;
    float ev[16];
    float s = 0.f;
#pragma unroll
    for (int j = 0; j < 16; ++j) { ev[j] = __expf(a1[j][r]); s += ev[j]; }
    s += __shfl_xor(s, 1); s += __shfl_xor(s, 2);
    s += __shfl_xor(s, 4); s += __shfl_xor(s, 8);
    rs[r] = s;
#pragma unroll
    for (int j = 0; j < 16; ++j) {
      float other = __shfl_xor(ev[j], 1);
      if ((lm & 1) == 0) {
        unsigned int w = f2bu(ev[j]) | ((unsigned)f2bu(other) << 16);
        *(unsigned int*)(Pl + rowl * 264 + j * 16 + lm) = w;
      }
    }
  }
  f32x4 a2[4];
#pragma unroll
  for (int j = 0; j < 4; ++j) a2[j] = (f32x4)0.0f;
  for (int k0 = 0; k0 < 256; k0 += 32) {
    stageA<64, 0>(WtA, 256, 0, k0, Bw, t);
    __syncthreads();
    bf16x8 af = *(const bf16x8*)(Pl + (wv * 16 + lm) * 264 + k0 + qd * 8);
#pragma unroll
    for (int j = 0; j < 4; ++j) {
      bf16x8 bf = *(const bf16x8*)(Bw + (j * 16 + lm) * 40 + qd * 8);
      a2[j] = mfma16(af, bf, a2[j]);
    }
    __syncthreads();
  }
#pragma unroll
  for (int j = 0; j < 4; ++j)
#pragma unroll
    for (int r = 0; r < 4; ++r) {
      long grow = m0 + wv * 16 + qd * 4 + r;
      long col = j * 16 + lm;
      oh[(bz * 4096 + grow) * 64 + col] = (bf16)(a2[j][r] / rs[r]);
    }
}

// depthwise conv residual, LDS-tiled sliding window, oh (bf16) += conv(v)
__global__ __launch_bounds__(256) void k_conv2(const bf16* __restrict__ v,
                                               const float* __restrict__ kern,
                                               bf16* __restrict__ oh) {
  __shared__ __align__(16) bf16 Vs[96 * 72];
  int bx = blockIdx.x;
  int bh = bx >> 6;
  int i0 = (bx & 63) * 64;
  int t = threadIdx.x;
  const bf16* vsrc = v + (long)bh * 262144;
#pragma unroll
  for (int c = 0; c < 3; ++c) {
    int idx = t + 256 * c;
    int r = idx >> 3, dc = (idx & 7) * 8;
    int grow = i0 + r - 16;
    bf16x8 val = (bf16x8)(bf16)0.0f;
    if (grow >= 0 && grow < 4096) val = *(const bf16x8*)(vsrc + (long)grow * 64 + dc);
    *(bf16x8*)(Vs + r * 72 + dc) = val;
  }
  __syncthreads();
  int dg = t & 15, rg = t >> 4;
  const float* kc = kern + (bh & 7) * 33;
  float acc[4][4] = {};
#pragma unroll
  for (int rr = 0; rr < 36; ++rr) {
    bf16x4 xv = *(const bf16x4*)(Vs + (rg * 4 + rr) * 72 + dg * 4);
    float x0 = (float)xv[0], x1 = (float)xv[1], x2 = (float)xv[2], x3 = (float)xv[3];
#pragma unroll
    for (int r = 0; r < 4; ++r) {
      int u = rr - r;
      if (u >= 0 && u < 33) {
        float kw = kc[u];
        acc[r][0] = fmaf(kw, x0, acc[r][0]);
        acc[r][1] = fmaf(kw, x1, acc[r][1]);
        acc[r][2] = fmaf(kw, x2, acc[r][2]);
        acc[r][3] = fmaf(kw, x3, acc[r][3]);
      }
    }
  }
  long base = ((long)bh * 4096 + i0 + rg * 4) * 64 + dg * 4;
#pragma unroll
  for (int r = 0; r < 4; ++r) {
    bf16x4 o = *(const bf16x4*)(oh + base + r * 64);
    bf16x4 w;
#pragma unroll
    for (int c = 0; c < 4; ++c) w[c] = (bf16)(acc[r][c] + (float)o[c]);
    *(bf16x4*)(oh + base + r * 64) = w;
  }
}

// ---------------- host ----------------
extern "C" void kernel_launch(void* const* d_in, const int* in_sizes, int n_in,
                              void* d_out, int out_size, void* d_ws, size_t ws_size,
                              hipStream_t stream) {
  const float* x     = (const float*)d_in[0];
  const float* w_qkv = (const float*)d_in[1];
  const float* w_out = (const float*)d_in[2];
  const float* b_out = (const float*)d_in[3];
  const float* res_k = (const float*)d_in[4];

  char* w = (char*)d_ws;
  bf16* qb  = (bf16*)(w);
  bf16* kb  = (bf16*)(w + 16777216);
  bf16* vb  = (bf16*)(w + 33554432);
  bf16* qlh = (bf16*)(w + 50331648);
  bf16* qll = (bf16*)(w + 51380224);
  bf16* klh = (bf16*)(w + 52428800);
  bf16* kll = (bf16*)(w + 53477376);
  bf16* A2h = (bf16*)(w + 54525952);
  bf16* A2l = (bf16*)(w + 58720256);
  bf16* zAh = (bf16*)(w + 62914560);
  bf16* zAl = (bf16*)(w + 67108864);
  bf16* zBh = (bf16*)(w + 71303168);
  bf16* zBl = (bf16*)(w + 75497472);
  bf16* yh  = (bf16*)(w + 79691776);
  bf16* yl  = (bf16*)(w + 83886080);
  bf16* bbh = (bf16*)(w + 88080384);
  bf16* bbl = (bf16*)(w + 92274688);
  bf16* cch = (bf16*)(w + 96468992);
  bf16* ccl = (bf16*)(w + 100663296);
  bf16* oh  = (bf16*)(w + 104857600);       // 16.8 MB bf16
  float* a3vf = (float*)(w + 121634816);    // 2 MB
  bf16* a3vh = (bf16*)(w + 123731968);
  bf16* a3vl = (bf16*)(w + 124780544);
  bf16* Wt   = (bf16*)(w + 125829120);
  float* rs3 = (float*)(w + 126877696);
  unsigned int* sc  = (unsigned int*)(w + 126910464);
  unsigned int* cnt = (unsigned int*)(w + 126910468);

  k_zero<<<2048, 256, 0, stream>>>(a3vf, rs3, sc, cnt);

  // qkv projection (fp32 in, bf16 head-layout out, q scaled)
  GP p{};
  p.A = x; p.ldA = 512; p.B = w_qkv; p.ldB = 1536; p.K = 512;
  p.C0 = qb; p.C1 = kb; p.C2 = vb;
  mgemm<128, 128, 2, 1, 2, 0, EQKV><<<dim3(12, 128, 1), 256, 0, stream>>>(p);

  k_landmarks<<<8192, 64, 0, stream>>>(qb, kb, qlh, qll, klh, kll);

  MegaP mp;
  mp.qlh = qlh; mp.qll = qll; mp.klh = klh; mp.kll = kll; mp.kb = kb; mp.vb = vb;
  mp.A2h = A2h; mp.A2l = A2l; mp.zAh = zAh; mp.zAl = zAl; mp.zBh = zBh; mp.zBl = zBl;
  mp.yh = yh; mp.yl = yl; mp.bbh = bbh; mp.bbl = bbl; mp.cch = cch; mp.ccl = ccl;
  mp.a3vf = a3vf; mp.rs3 = rs3; mp.sc = sc; mp.cnt = cnt;
  mp.a3vh = a3vh; mp.a3vl = a3vl; mp.Wt = Wt;
  k_mega<<<512, 256, 0, stream>>>(mp);

  // oh = softmax(q @ kl^T) @ W (fused), bf16 out
  k_attn1w<<<dim3(64, 1, 32), 256, 0, stream>>>(qb, klh, Wt, oh);

  // += depthwise conv residual
  k_conv2<<<2048, 256, 0, stream>>>(vb, res_k, oh);

  // out = gather(oh bf16) @ w_out + bias
  p = GP{};
  p.A = oh; p.B = w_out; p.ldB = 512; p.K = 512;
  p.C0 = d_out; p.bias = b_out;
  mgemm<128, 128, 2, 3, 2, 0, EBIAS><<<dim3(4, 128, 1), 256, 0, stream>>>(p);
}

// Round 4
// 645.053 us; speedup vs baseline: 5.5818x; 5.5818x over previous
//
#include <hip/hip_runtime.h>

// ---------------- problem constants ----------------
#define Nq   4096
#define DHq  64
#define Mq   256
#define BHq  32

using bf16 = __bf16;
using bf16x8 = __bf16 __attribute__((ext_vector_type(8)));
using bf16x4 = __bf16 __attribute__((ext_vector_type(4)));
using f32x4 = float __attribute__((ext_vector_type(4)));

__device__ __forceinline__ f32x4 mfma16(bf16x8 a, bf16x8 b, f32x4 c) {
  return __builtin_amdgcn_mfma_f32_16x16x32_bf16(a, b, c, 0, 0, 0);
}
__device__ __forceinline__ unsigned short f2bu(float f) {
  bf16 b = (bf16)f;
  return __builtin_bit_cast(unsigned short, b);
}
__device__ __forceinline__ void split_store(bf16* h, bf16* l, long idx, float v) {
  bf16 hi = (bf16)v;
  h[idx] = hi;
  l[idx] = (bf16)(v - (float)hi);
}

// Stage a ROWS x 32 bf16 tile into LDS, row stride 40 bf16 (80 B).
// SRC: 0 = bf16 row-major, 1 = f32 row-major, 3 = bf16 gather from oh[bh][4096][64]
template<int ROWS, int SRC>
__device__ __forceinline__ void stageA(const void* src, long ld, long row0, int k0,
                                       bf16* dst, int t) {
#pragma unroll
  for (int c = 0; c < ROWS / 64; ++c) {
    int idx = t + 256 * c;
    int r = idx >> 2;
    int kc = (idx & 3) << 3;
    bf16x8 val;
    if constexpr (SRC == 0) {
      val = *(const bf16x8*)((const bf16*)src + (row0 + r) * ld + k0 + kc);
    } else if constexpr (SRC == 1) {
      const float* s = (const float*)src + (row0 + r) * ld + k0 + kc;
      float4 a = *(const float4*)s;
      float4 b = *(const float4*)(s + 4);
      val[0]=(bf16)a.x; val[1]=(bf16)a.y; val[2]=(bf16)a.z; val[3]=(bf16)a.w;
      val[4]=(bf16)b.x; val[5]=(bf16)b.y; val[6]=(bf16)b.z; val[7]=(bf16)b.w;
    } else {
      long m = row0 + r;
      long bb = m >> 12, ii = m & 4095;
      int k = k0 + kc;
      long h = k >> 6, d = k & 63;
      val = *(const bf16x8*)((const bf16*)src + (((bb * 8 + h) * 4096 + ii) * 64 + d));
    }
    *(bf16x8*)(dst + r * 40 + kc) = val;
  }
}

// Stage 32 x COLS tile of row-major [K][N] B into word-LDS [COLS][20 words].
template<int COLS, bool F32>
__device__ __forceinline__ void stageBN(const void* src, long ld, long n0, int k0,
                                        unsigned int* dst, int t) {
  int kp = t >> 4;
  int nb = (t & 15) << 2;
#pragma unroll
  for (int g = 0; g < COLS / 64; ++g) {
    int n = nb + (g << 6);
    unsigned int w0, w1, w2, w3;
    if constexpr (F32) {
      const float* s0 = (const float*)src + (long)(k0 + 2 * kp) * ld + n0 + n;
      const float* s1 = s0 + ld;
      float4 a = *(const float4*)s0;
      float4 b = *(const float4*)s1;
      w0 = f2bu(a.x) | ((unsigned)f2bu(b.x) << 16);
      w1 = f2bu(a.y) | ((unsigned)f2bu(b.y) << 16);
      w2 = f2bu(a.z) | ((unsigned)f2bu(b.z) << 16);
      w3 = f2bu(a.w) | ((unsigned)f2bu(b.w) << 16);
    } else {
      const unsigned short* s0 = (const unsigned short*)src + (long)(k0 + 2 * kp) * ld + n0 + n;
      const unsigned short* s1 = s0 + ld;
      ushort4 a = *(const ushort4*)s0;
      ushort4 b = *(const ushort4*)s1;
      w0 = a.x | ((unsigned)b.x << 16);
      w1 = a.y | ((unsigned)b.y << 16);
      w2 = a.z | ((unsigned)b.z << 16);
      w3 = a.w | ((unsigned)b.w << 16);
    }
    dst[(n + 0) * 20 + kp] = w0;
    dst[(n + 1) * 20 + kp] = w1;
    dst[(n + 2) * 20 + kp] = w2;
    dst[(n + 3) * 20 + kp] = w3;
  }
}

#define EQKV 0
#define EA2 1
#define EY 4
#define EG2 5
#define EG3 6
#define EG4 7
#define EWT 8
#define EBIAS 9

struct GP {
  const void* A; const void* Al;
  const void* B; const void* Bl;
  long ldA, ldB, sA, sB;
  int K;
  void* C0; void* C1; void* C2;
  long sC, ldC;
  const void* x0; const void* x1;
  const float* bias;
};

template<int BM, int BN, int WX, int ASRC, int BMODE, int SPLIT, int EPI>
__global__ __launch_bounds__(256, 2) void mgemm(GP p) {
  constexpr int WY = 4 / WX;
  constexpr int TM = BM / WY, TN = BN / WX;
  constexpr int IT = TM / 16, JT = TN / 16;
  constexpr int AB = (SPLIT ? 2 : 1) * BM * 80;
  constexpr int BB = (SPLIT ? 2 : 1) * BN * 80;
  __shared__ __align__(16) char Lbuf[AB + BB];
  bf16* AsL = (bf16*)Lbuf;
  unsigned int* BsL = (unsigned int*)(Lbuf + AB);
  int t = threadIdx.x;
  int wv = t >> 6, lane = t & 63;
  int wy = wv / WX, wx = wv % WX;
  int qd = lane >> 4, lm = lane & 15;
  long bz = blockIdx.z;
  long m0 = (long)blockIdx.y * BM, n0 = (long)blockIdx.x * BN;

  const void* Ap; const void* Alp = nullptr;
  if constexpr (ASRC == 0) Ap = (const bf16*)p.A + bz * p.sA;
  else Ap = p.A;
  if constexpr (SPLIT) Alp = (const bf16*)p.Al + bz * p.sA;
  const void* Bp; const void* Blp = nullptr;
  if constexpr (BMODE == 2) Bp = p.B;
  else Bp = (const bf16*)p.B + bz * p.sB;
  if constexpr (SPLIT) Blp = (const bf16*)p.Bl + bz * p.sB;

  f32x4 acc[IT][JT];
#pragma unroll
  for (int i = 0; i < IT; ++i)
#pragma unroll
    for (int j = 0; j < JT; ++j) acc[i][j] = (f32x4)0.0f;

  for (int k0 = 0; k0 < p.K; k0 += 32) {
    stageA<BM, ASRC>(Ap, p.ldA, m0, k0, AsL, t);
    if constexpr (SPLIT) stageA<BM, 0>(Alp, p.ldA, m0, k0, AsL + BM * 40, t);
    if constexpr (BMODE == 0) {
      stageA<BN, 0>(Bp, p.ldB, n0, k0, (bf16*)BsL, t);
      if constexpr (SPLIT) stageA<BN, 0>(Blp, p.ldB, n0, k0, (bf16*)BsL + BN * 40, t);
    } else {
      stageBN<BN, BMODE == 2>(Bp, p.ldB, n0, k0, BsL, t);
      if constexpr (SPLIT) stageBN<BN, false>(Blp, p.ldB, n0, k0, BsL + BN * 20, t);
    }
    __syncthreads();
    bf16x8 af[IT], afl[IT];
#pragma unroll
    for (int i = 0; i < IT; ++i) {
      int m = wy * TM + i * 16 + lm;
      af[i] = *(const bf16x8*)(AsL + m * 40 + qd * 8);
      if constexpr (SPLIT) afl[i] = *(const bf16x8*)(AsL + BM * 40 + m * 40 + qd * 8);
    }
#pragma unroll
    for (int j = 0; j < JT; ++j) {
      int n = wx * TN + j * 16 + lm;
      bf16x8 bf, bfl;
      if constexpr (BMODE == 0) {
        bf = *(const bf16x8*)((const bf16*)BsL + n * 40 + qd * 8);
        if constexpr (SPLIT) bfl = *(const bf16x8*)((const bf16*)BsL + BN * 40 + n * 40 + qd * 8);
      } else {
        bf = *(const bf16x8*)((const bf16*)(BsL + n * 20 + qd * 4));
        if constexpr (SPLIT) bfl = *(const bf16x8*)((const bf16*)(BsL + BN * 20 + n * 20 + qd * 4));
      }
#pragma unroll
      for (int i = 0; i < IT; ++i) {
        acc[i][j] = mfma16(af[i], bf, acc[i][j]);
        if constexpr (SPLIT) {
          acc[i][j] = mfma16(af[i], bfl, acc[i][j]);
          acc[i][j] = mfma16(afl[i], bf, acc[i][j]);
        }
      }
    }
    __syncthreads();
  }

  if constexpr (EPI == EA2) {
#pragma unroll
    for (int r = 0; r < 4; ++r) {
      long row = m0 + wy * TM + qd * 4 + r;
      float e[JT];
      float s = 0.f;
#pragma unroll
      for (int j = 0; j < JT; ++j) { e[j] = __expf(acc[0][j][r]); s += e[j]; }
      s += __shfl_xor(s, 1); s += __shfl_xor(s, 2);
      s += __shfl_xor(s, 4); s += __shfl_xor(s, 8);
      float inv = 1.0f / s;
#pragma unroll
      for (int j = 0; j < JT; ++j) {
        long col = n0 + j * 16 + lm;
        split_store((bf16*)p.C0, (bf16*)p.C1, bz * p.sC + row * p.ldC + col, e[j] * inv);
      }
    }
  } else {
#pragma unroll
    for (int i = 0; i < IT; ++i)
#pragma unroll
      for (int j = 0; j < JT; ++j)
#pragma unroll
        for (int r = 0; r < 4; ++r) {
          long row = m0 + wy * TM + i * 16 + qd * 4 + r;
          long col = n0 + wx * TN + j * 16 + lm;
          float v = acc[i][j][r];
          if constexpr (EPI == EQKV) {
            int part = (int)(col >> 9);
            long h = (col >> 6) & 7, d = col & 63;
            long bb = row >> 12, ii = row & 4095;
            float scv = part == 0 ? 0.125f : 1.0f;
            bf16* dst = part == 0 ? (bf16*)p.C0 : (part == 1 ? (bf16*)p.C1 : (bf16*)p.C2);
            dst[((bb * 8 + h) * 4096 + ii) * 64 + d] = (bf16)(v * scv);
          } else if constexpr (EPI == EY) {
            split_store((bf16*)p.C0, (bf16*)p.C1, bz * 65536 + row * 256 + col, v);
          } else if constexpr (EPI == EG2) {
            long ix = bz * 65536 + row * 256 + col;
            float y = (float)((const bf16*)p.x0)[ix] + (float)((const bf16*)p.x1)[ix];
            float val = (row == col ? 15.0f : 0.0f) - 7.0f * y + v;
            split_store((bf16*)p.C0, (bf16*)p.C1, ix, val);
          } else if constexpr (EPI == EG3) {
            float val = (row == col ? 13.0f : 0.0f) - v;
            split_store((bf16*)p.C0, (bf16*)p.C1, bz * 65536 + row * 256 + col, val);
          } else if constexpr (EPI == EG4) {
            split_store((bf16*)p.C0, (bf16*)p.C1, bz * 65536 + row * 256 + col, 0.25f * v);
          } else if constexpr (EPI == EWT) {
            ((bf16*)p.C0)[bz * 16384 + col * 256 + row] = (bf16)v;
          } else if constexpr (EPI == EBIAS) {
            ((float*)p.C0)[row * 512 + col] = v + p.bias[col];
          }
        }
  }
}

// ---------------- flash a3v: accumulate exp(ql k^T) v into fp32 + row sums ------
// grid 512: bh (32) x qt (4) x kt (4); kt strip = 1024 kv rows.
__global__ __launch_bounds__(256, 2) void k_a3v(const bf16* __restrict__ qlh,
                                                const bf16* __restrict__ kb,
                                                const bf16* __restrict__ vb,
                                                float* __restrict__ a3vf,
                                                float* __restrict__ rs3) {
  __shared__ __align__(16) char L[38400];
  bf16* qlS = (bf16*)L;                     // [64][72]
  bf16* kS  = (bf16*)(L + 9216);            // [64][72]
  bf16* PA  = (bf16*)(L + 18432);           // [64][72]
  unsigned int* vB0 = (unsigned int*)(L + 27648);  // [64][20]
  unsigned int* vB1 = (unsigned int*)(L + 32768);  // [64][20]
  float* rsL = (float*)(L + 37888);         // [64][2]
  int b = blockIdx.x, t = threadIdx.x;
  long bz = b >> 4;
  int qt = (b >> 2) & 3, kt = b & 3;
  int wv = t >> 6, lane = t & 63, qd = lane >> 4, lm = lane & 15;
  int wy = wv >> 1, wx = wv & 1;
  const bf16* qlp = qlh + bz * 16384 + qt * 64 * 64;
#pragma unroll
  for (int c = 0; c < 2; ++c) {
    int idx = t + 256 * c;
    int r = idx >> 3, dc = (idx & 7) * 8;
    *(bf16x8*)(qlS + r * 72 + dc) = *(const bf16x8*)(qlp + r * 64 + dc);
  }
  const bf16* kb_ = kb + bz * 262144 + (long)kt * 65536;
  const bf16* vb_ = vb + bz * 262144 + (long)kt * 65536;
  f32x4 accO[2][2];
  float rsum[2][4];
#pragma unroll
  for (int i = 0; i < 2; ++i) {
#pragma unroll
    for (int j = 0; j < 2; ++j) accO[i][j] = (f32x4)0.0f;
#pragma unroll
    for (int r = 0; r < 4; ++r) rsum[i][r] = 0.f;
  }
  for (int tt = 0; tt < 16; ++tt) {
    __syncthreads();
    const bf16* ks_ = kb_ + tt * 4096;
#pragma unroll
    for (int c = 0; c < 2; ++c) {
      int idx = t + 256 * c;
      int r = idx >> 3, dc = (idx & 7) * 8;
      *(bf16x8*)(kS + r * 72 + dc) = *(const bf16x8*)(ks_ + r * 64 + dc);
    }
    const bf16* vs_ = vb_ + tt * 4096;
    stageBN<64, false>(vs_, 64, 0, 0, vB0, t);
    stageBN<64, false>(vs_, 64, 0, 32, vB1, t);
    __syncthreads();
    f32x4 s[2][2];
#pragma unroll
    for (int i = 0; i < 2; ++i)
#pragma unroll
      for (int j = 0; j < 2; ++j) s[i][j] = (f32x4)0.0f;
#pragma unroll
    for (int ks = 0; ks < 2; ++ks) {
      bf16x8 af[2], bfv[2];
#pragma unroll
      for (int i = 0; i < 2; ++i)
        af[i] = *(const bf16x8*)(qlS + (wy * 32 + i * 16 + lm) * 72 + ks * 32 + qd * 8);
#pragma unroll
      for (int j = 0; j < 2; ++j)
        bfv[j] = *(const bf16x8*)(kS + (wx * 32 + j * 16 + lm) * 72 + ks * 32 + qd * 8);
#pragma unroll
      for (int i = 0; i < 2; ++i)
#pragma unroll
        for (int j = 0; j < 2; ++j) s[i][j] = mfma16(af[i], bfv[j], s[i][j]);
    }
#pragma unroll
    for (int i = 0; i < 2; ++i)
#pragma unroll
      for (int r = 0; r < 4; ++r) {
        float e0 = __expf(s[i][0][r]);
        float e1 = __expf(s[i][1][r]);
        int row = wy * 32 + i * 16 + qd * 4 + r;
        PA[row * 72 + wx * 32 + 0 * 16 + lm] = (bf16)e0;
        PA[row * 72 + wx * 32 + 1 * 16 + lm] = (bf16)e1;
        float cs = e0 + e1;
        cs += __shfl_xor(cs, 1); cs += __shfl_xor(cs, 2);
        cs += __shfl_xor(cs, 4); cs += __shfl_xor(cs, 8);
        rsum[i][r] += cs;
      }
    __syncthreads();
#pragma unroll
    for (int ks = 0; ks < 2; ++ks) {
      unsigned int* vB = ks ? vB1 : vB0;
      bf16x8 af[2], bfv[2];
#pragma unroll
      for (int i = 0; i < 2; ++i)
        af[i] = *(const bf16x8*)(PA + (wy * 32 + i * 16 + lm) * 72 + ks * 32 + qd * 8);
#pragma unroll
      for (int j = 0; j < 2; ++j)
        bfv[j] = *(const bf16x8*)((const bf16*)(vB + (wx * 32 + j * 16 + lm) * 20) + qd * 8);
#pragma unroll
      for (int i = 0; i < 2; ++i)
#pragma unroll
        for (int j = 0; j < 2; ++j) accO[i][j] = mfma16(af[i], bfv[j], accO[i][j]);
    }
  }
  if (lm == 0) {
#pragma unroll
    for (int i = 0; i < 2; ++i)
#pragma unroll
      for (int r = 0; r < 4; ++r)
        rsL[(wy * 32 + i * 16 + qd * 4 + r) * 2 + wx] = rsum[i][r];
  }
  __syncthreads();
  if (t < 64) atomicAdd(&rs3[bz * 256 + qt * 64 + t], rsL[t * 2] + rsL[t * 2 + 1]);
#pragma unroll
  for (int i = 0; i < 2; ++i)
#pragma unroll
    for (int j = 0; j < 2; ++j)
#pragma unroll
      for (int r = 0; r < 4; ++r) {
        long row = bz * 256 + qt * 64 + wy * 32 + i * 16 + qd * 4 + r;
        long col = wx * 32 + j * 16 + lm;
        atomicAdd(&a3vf[row * 64 + col], accO[i][j][r]);
      }
}

__global__ void k_a3vnorm(const float* __restrict__ a3vf, const float* __restrict__ rs3,
                          bf16* __restrict__ a3vh, bf16* __restrict__ a3vl) {
  long e0 = ((long)blockIdx.x * 256 + threadIdx.x) * 4;
  float4 vv = *(const float4*)&a3vf[e0];
  float inv = 1.0f / rs3[e0 >> 6];
  split_store(a3vh, a3vl, e0 + 0, vv.x * inv);
  split_store(a3vh, a3vl, e0 + 1, vv.y * inv);
  split_store(a3vh, a3vl, e0 + 2, vv.z * inv);
  split_store(a3vh, a3vl, e0 + 3, vv.w * inv);
}

// ---------------- small kernels ----------------
__global__ void k_zero(float* a3vf, float* rs3, unsigned int* sc) {
  long i = (long)blockIdx.x * 256 + threadIdx.x;
  a3vf[i] = 0.f;
  if (i < 8192) rs3[i] = 0.f;
  if (i == 0) sc[0] = 0u;
}

__global__ void k_landmarks(const bf16* q, const bf16* k, bf16* qlh, bf16* qll,
                            bf16* klh, bf16* kll) {
  int bm = blockIdx.x;
  int bh = bm >> 8, mi = bm & 255;
  int d = threadIdx.x;
  const bf16* qp = q + ((long)bh * 4096 + mi * 16) * 64 + d;
  const bf16* kp = k + ((long)bh * 4096 + mi * 16) * 64 + d;
  float sq = 0.f, sk = 0.f;
#pragma unroll
  for (int tt = 0; tt < 16; ++tt) { sq += (float)qp[tt * 64]; sk += (float)kp[tt * 64]; }
  sq *= 0.0625f; sk *= 0.0625f;
  long o = (long)bh * 16384 + mi * 64 + d;
  split_store(qlh, qll, o, sq);
  split_store(klh, kll, o, sk);
}

__global__ __launch_bounds__(256) void k_colsum(const bf16* A2h, const bf16* A2l,
                                                unsigned int* sc) {
  int bh = blockIdx.x, j = threadIdx.x;
  const bf16* ph = A2h + (long)bh * 65536 + j;
  const bf16* pl = A2l + (long)bh * 65536 + j;
  float s = 0.f;
  for (int i = 0; i < 256; ++i) s += (float)ph[i * 256] + (float)pl[i * 256];
  __shared__ float red[256];
  red[j] = s; __syncthreads();
  for (int o = 128; o > 0; o >>= 1) {
    if (j < o) red[j] = fmaxf(red[j], red[j + o]);
    __syncthreads();
  }
  if (j == 0) atomicMax(sc, __float_as_uint(red[0]));
}

__global__ __launch_bounds__(256) void k_zinit(const bf16* A2h, const bf16* A2l,
                                               const unsigned int* sc, bf16* zh, bf16* zl) {
  __shared__ float T[64][65];
  int bh = blockIdx.z, ti = blockIdx.y, tj = blockIdx.x;
  int t = threadIdx.x;
  int c = t & 63, r0 = t >> 6;
  long base = (long)bh * 65536;
  float inv = 1.0f / __uint_as_float(sc[0]);
#pragma unroll
  for (int rr = 0; rr < 16; ++rr) {
    int r = r0 * 16 + rr;
    long idx = base + (long)(ti * 64 + r) * 256 + tj * 64 + c;
    T[r][c] = (float)A2h[idx] + (float)A2l[idx];
  }
  __syncthreads();
#pragma unroll
  for (int rr = 0; rr < 16; ++rr) {
    int jl = r0 * 16 + rr;
    float v = T[c][jl] * inv;
    long o = base + (long)(tj * 64 + jl) * 256 + ti * 64 + c;
    split_store(zh, zl, o, v);
  }
}

// fused: oh = softmax(q @ kl^T) @ W  (bf16 out), Wt [bh][64][256]
__global__ __launch_bounds__(256, 2) void k_attn1w(const bf16* qb, const bf16* klb,
                                                   const bf16* Wt, bf16* oh) {
  __shared__ __align__(16) char L[38912];
  bf16* Aq = (bf16*)L;             // [64][40]
  bf16* Bkl = (bf16*)(L + 5120);   // [256][40]
  bf16* Pl = (bf16*)L;             // [64][264] (reuse after stage-1)
  bf16* Bw = (bf16*)(L + 33792);   // [64][40]
  int t = threadIdx.x, wv = t >> 6, lane = t & 63;
  int qd = lane >> 4, lm = lane & 15;
  long bz = blockIdx.z;
  long m0 = (long)blockIdx.x * 64;
  const bf16* qA = qb + bz * (4096L * 64);
  const bf16* klA = klb + bz * (256L * 64);
  const bf16* WtA = Wt + bz * 16384;

  f32x4 a1[16];
#pragma unroll
  for (int j = 0; j < 16; ++j) a1[j] = (f32x4)0.0f;
  for (int k0 = 0; k0 < 64; k0 += 32) {
    stageA<64, 0>(qA, 64, m0, k0, Aq, t);
    stageA<256, 0>(klA, 64, 0, k0, Bkl, t);
    __syncthreads();
    bf16x8 af = *(const bf16x8*)(Aq + (wv * 16 + lm) * 40 + qd * 8);
#pragma unroll
    for (int j = 0; j < 16; ++j) {
      bf16x8 bf = *(const bf16x8*)(Bkl + (j * 16 + lm) * 40 + qd * 8);
      a1[j] = mfma16(af, bf, a1[j]);
    }
    __syncthreads();
  }
  float rs[4];
#pragma unroll
  for (int r = 0; r < 4; ++r) {
    int rowl = wv * 16 + qd * 4 + r;
    float ev[16];
    float s = 0.f;
#pragma unroll
    for (int j = 0; j < 16; ++j) { ev[j] = __expf(a1[j][r]); s += ev[j]; }
    s += __shfl_xor(s, 1); s += __shfl_xor(s, 2);
    s += __shfl_xor(s, 4); s += __shfl_xor(s, 8);
    rs[r] = s;
#pragma unroll
    for (int j = 0; j < 16; ++j) {
      float other = __shfl_xor(ev[j], 1);
      if ((lm & 1) == 0) {
        unsigned int w = f2bu(ev[j]) | ((unsigned)f2bu(other) << 16);
        *(unsigned int*)(Pl + rowl * 264 + j * 16 + lm) = w;
      }
    }
  }
  f32x4 a2[4];
#pragma unroll
  for (int j = 0; j < 4; ++j) a2[j] = (f32x4)0.0f;
  for (int k0 = 0; k0 < 256; k0 += 32) {
    stageA<64, 0>(WtA, 256, 0, k0, Bw, t);
    __syncthreads();
    bf16x8 af = *(const bf16x8*)(Pl + (wv * 16 + lm) * 264 + k0 + qd * 8);
#pragma unroll
    for (int j = 0; j < 4; ++j) {
      bf16x8 bf = *(const bf16x8*)(Bw + (j * 16 + lm) * 40 + qd * 8);
      a2[j] = mfma16(af, bf, a2[j]);
    }
    __syncthreads();
  }
#pragma unroll
  for (int j = 0; j < 4; ++j)
#pragma unroll
    for (int r = 0; r < 4; ++r) {
      long grow = m0 + wv * 16 + qd * 4 + r;
      long col = j * 16 + lm;
      oh[(bz * 4096 + grow) * 64 + col] = (bf16)(a2[j][r] / rs[r]);
    }
}

// depthwise conv residual, LDS-tiled sliding window, oh (bf16) += conv(v)
__global__ __launch_bounds__(256) void k_conv2(const bf16* __restrict__ v,
                                               const float* __restrict__ kern,
                                               bf16* __restrict__ oh) {
  __shared__ __align__(16) bf16 Vs[96 * 72];
  int bx = blockIdx.x;
  int bh = bx >> 6;
  int i0 = (bx & 63) * 64;
  int t = threadIdx.x;
  const bf16* vsrc = v + (long)bh * 262144;
#pragma unroll
  for (int c = 0; c < 3; ++c) {
    int idx = t + 256 * c;
    int r = idx >> 3, dc = (idx & 7) * 8;
    int grow = i0 + r - 16;
    bf16x8 val = (bf16x8)(bf16)0.0f;
    if (grow >= 0 && grow < 4096) val = *(const bf16x8*)(vsrc + (long)grow * 64 + dc);
    *(bf16x8*)(Vs + r * 72 + dc) = val;
  }
  __syncthreads();
  int dg = t & 15, rg = t >> 4;
  const float* kc = kern + (bh & 7) * 33;
  float acc[4][4] = {};
#pragma unroll
  for (int rr = 0; rr < 36; ++rr) {
    bf16x4 xv = *(const bf16x4*)(Vs + (rg * 4 + rr) * 72 + dg * 4);
    float x0 = (float)xv[0], x1 = (float)xv[1], x2 = (float)xv[2], x3 = (float)xv[3];
#pragma unroll
    for (int r = 0; r < 4; ++r) {
      int u = rr - r;
      if (u >= 0 && u < 33) {
        float kw = kc[u];
        acc[r][0] = fmaf(kw, x0, acc[r][0]);
        acc[r][1] = fmaf(kw, x1, acc[r][1]);
        acc[r][2] = fmaf(kw, x2, acc[r][2]);
        acc[r][3] = fmaf(kw, x3, acc[r][3]);
      }
    }
  }
  long base = ((long)bh * 4096 + i0 + rg * 4) * 64 + dg * 4;
#pragma unroll
  for (int r = 0; r < 4; ++r) {
    bf16x4 o = *(const bf16x4*)(oh + base + r * 64);
    bf16x4 w;
#pragma unroll
    for (int c = 0; c < 4; ++c) w[c] = (bf16)(acc[r][c] + (float)o[c]);
    *(bf16x4*)(oh + base + r * 64) = w;
  }
}

// ---------------- host ----------------
extern "C" void kernel_launch(void* const* d_in, const int* in_sizes, int n_in,
                              void* d_out, int out_size, void* d_ws, size_t ws_size,
                              hipStream_t stream) {
  const float* x     = (const float*)d_in[0];
  const float* w_qkv = (const float*)d_in[1];
  const float* w_out = (const float*)d_in[2];
  const float* b_out = (const float*)d_in[3];
  const float* res_k = (const float*)d_in[4];

  char* w = (char*)d_ws;
  bf16* qb  = (bf16*)(w);
  bf16* kb  = (bf16*)(w + 16777216);
  bf16* vb  = (bf16*)(w + 33554432);
  bf16* qlh = (bf16*)(w + 50331648);
  bf16* qll = (bf16*)(w + 51380224);
  bf16* klh = (bf16*)(w + 52428800);
  bf16* kll = (bf16*)(w + 53477376);
  bf16* A2h = (bf16*)(w + 54525952);
  bf16* A2l = (bf16*)(w + 58720256);
  bf16* zAh = (bf16*)(w + 62914560);
  bf16* zAl = (bf16*)(w + 67108864);
  bf16* zBh = (bf16*)(w + 71303168);
  bf16* zBl = (bf16*)(w + 75497472);
  bf16* yh  = (bf16*)(w + 79691776);
  bf16* yl  = (bf16*)(w + 83886080);
  bf16* bbh = (bf16*)(w + 88080384);
  bf16* bbl = (bf16*)(w + 92274688);
  bf16* cch = (bf16*)(w + 96468992);
  bf16* ccl = (bf16*)(w + 100663296);
  bf16* oh  = (bf16*)(w + 104857600);       // 16.8 MB bf16
  float* a3vf = (float*)(w + 121634816);    // 2 MB
  bf16* a3vh = (bf16*)(w + 123731968);
  bf16* a3vl = (bf16*)(w + 124780544);
  bf16* Wt   = (bf16*)(w + 125829120);
  float* rs3 = (float*)(w + 126877696);
  unsigned int* sc  = (unsigned int*)(w + 126910464);

  k_zero<<<2048, 256, 0, stream>>>(a3vf, rs3, sc);

  // qkv projection (fp32 in, bf16 head-layout out, q scaled)
  GP p{};
  p.A = x; p.ldA = 512; p.B = w_qkv; p.ldB = 1536; p.K = 512;
  p.C0 = qb; p.C1 = kb; p.C2 = vb;
  mgemm<128, 128, 2, 1, 2, 0, EQKV><<<dim3(12, 128, 1), 256, 0, stream>>>(p);

  k_landmarks<<<8192, 64, 0, stream>>>(qb, kb, qlh, qll, klh, kll);

  // attn2 = softmax(ql @ kl^T), split-precision
  p = GP{};
  p.A = qlh; p.Al = qll; p.ldA = 64; p.sA = 16384;
  p.B = klh; p.Bl = kll; p.ldB = 64; p.sB = 16384; p.K = 64;
  p.C0 = A2h; p.C1 = A2l; p.sC = 65536; p.ldC = 256;
  mgemm<64, 256, 1, 0, 0, 1, EA2><<<dim3(1, 4, 32), 256, 0, stream>>>(p);

  k_colsum<<<32, 256, 0, stream>>>(A2h, A2l, sc);
  k_zinit<<<dim3(4, 4, 32), 256, 0, stream>>>(A2h, A2l, sc, zAh, zAl);

  // a3v = softmax(ql @ k^T) @ v  — flash accumulation + normalize
  k_a3v<<<512, 256, 0, stream>>>(qlh, kb, vb, a3vf, rs3);
  k_a3vnorm<<<512, 256, 0, stream>>>(a3vf, rs3, a3vh, a3vl);

  // Newton-Schulz pinv, split-bf16
  bf16 *zch = zAh, *zcl = zAl, *znh = zBh, *znl = zBl;
  for (int it = 0; it < 6; ++it) {
    p = GP{};
    p.ldA = 256; p.sA = 65536; p.ldB = 256; p.sB = 65536; p.K = 256;
    p.A = A2h; p.Al = A2l; p.B = zch; p.Bl = zcl;
    p.C0 = yh; p.C1 = yl;
    mgemm<64, 64, 2, 0, 1, 1, EY><<<dim3(4, 4, 32), 256, 0, stream>>>(p);
    p.A = yh; p.Al = yl; p.B = yh; p.Bl = yl;
    p.C0 = bbh; p.C1 = bbl; p.x0 = yh; p.x1 = yl;
    mgemm<64, 64, 2, 0, 1, 1, EG2><<<dim3(4, 4, 32), 256, 0, stream>>>(p);
    p.A = yh; p.Al = yl; p.B = bbh; p.Bl = bbl; p.C0 = cch; p.C1 = ccl;
    mgemm<64, 64, 2, 0, 1, 1, EG3><<<dim3(4, 4, 32), 256, 0, stream>>>(p);
    p.A = zch; p.Al = zcl; p.B = cch; p.Bl = ccl; p.C0 = znh; p.C1 = znl;
    mgemm<64, 64, 2, 0, 1, 1, EG4><<<dim3(4, 4, 32), 256, 0, stream>>>(p);
    bf16* tmp;
    tmp = zch; zch = znh; znh = tmp;
    tmp = zcl; zcl = znl; znl = tmp;
  }

  // Wt = (z @ a3v)^T
  p = GP{};
  p.A = zch; p.Al = zcl; p.ldA = 256; p.sA = 65536;
  p.B = a3vh; p.Bl = a3vl; p.ldB = 64; p.sB = 16384; p.K = 256;
  p.C0 = Wt;
  mgemm<64, 64, 2, 0, 1, 1, EWT><<<dim3(1, 4, 32), 256, 0, stream>>>(p);

  // oh = softmax(q @ kl^T) @ W (fused), bf16 out
  k_attn1w<<<dim3(64, 1, 32), 256, 0, stream>>>(qb, klh, Wt, oh);

  // += depthwise conv residual
  k_conv2<<<2048, 256, 0, stream>>>(vb, res_k, oh);

  // out = gather(oh bf16) @ w_out + bias
  p = GP{};
  p.A = oh; p.B = w_out; p.ldB = 512; p.K = 512;
  p.C0 = d_out; p.bias = b_out;
  mgemm<128, 128, 2, 3, 2, 0, EBIAS><<<dim3(4, 128, 1), 256, 0, stream>>>(p);
}

// Round 5
// 589.299 us; speedup vs baseline: 6.1099x; 1.0946x over previous
//
#include <hip/hip_runtime.h>

// ---------------- problem constants ----------------
#define Nq   4096
#define DHq  64
#define Mq   256
#define BHq  32

using bf16 = __bf16;
using bf16x8 = __bf16 __attribute__((ext_vector_type(8)));
using bf16x4 = __bf16 __attribute__((ext_vector_type(4)));
using f32x4 = float __attribute__((ext_vector_type(4)));

__device__ __forceinline__ f32x4 mfma16(bf16x8 a, bf16x8 b, f32x4 c) {
  return __builtin_amdgcn_mfma_f32_16x16x32_bf16(a, b, c, 0, 0, 0);
}
__device__ __forceinline__ unsigned short f2bu(float f) {
  bf16 b = (bf16)f;
  return __builtin_bit_cast(unsigned short, b);
}
__device__ __forceinline__ void split_store(bf16* h, bf16* l, long idx, float v) {
  bf16 hi = (bf16)v;
  h[idx] = hi;
  l[idx] = (bf16)(v - (float)hi);
}

// Stage a ROWS x 32 bf16 tile into LDS, row stride 40 bf16 (80 B).
// SRC: 0 = bf16 row-major, 1 = f32 row-major, 3 = bf16 gather from oh[bh][4096][64]
template<int ROWS, int SRC>
__device__ __forceinline__ void stageA(const void* src, long ld, long row0, int k0,
                                       bf16* dst, int t) {
#pragma unroll
  for (int c = 0; c < ROWS / 64; ++c) {
    int idx = t + 256 * c;
    int r = idx >> 2;
    int kc = (idx & 3) << 3;
    bf16x8 val;
    if constexpr (SRC == 0) {
      val = *(const bf16x8*)((const bf16*)src + (row0 + r) * ld + k0 + kc);
    } else if constexpr (SRC == 1) {
      const float* s = (const float*)src + (row0 + r) * ld + k0 + kc;
      float4 a = *(const float4*)s;
      float4 b = *(const float4*)(s + 4);
      val[0]=(bf16)a.x; val[1]=(bf16)a.y; val[2]=(bf16)a.z; val[3]=(bf16)a.w;
      val[4]=(bf16)b.x; val[5]=(bf16)b.y; val[6]=(bf16)b.z; val[7]=(bf16)b.w;
    } else {
      long m = row0 + r;
      long bb = m >> 12, ii = m & 4095;
      int k = k0 + kc;
      long h = k >> 6, d = k & 63;
      val = *(const bf16x8*)((const bf16*)src + (((bb * 8 + h) * 4096 + ii) * 64 + d));
    }
    *(bf16x8*)(dst + r * 40 + kc) = val;
  }
}

// Stage 32 x COLS tile of row-major [K][N] B into word-LDS [COLS][20 words].
template<int COLS, bool F32>
__device__ __forceinline__ void stageBN(const void* src, long ld, long n0, int k0,
                                        unsigned int* dst, int t) {
  int kp = t >> 4;
  int nb = (t & 15) << 2;
#pragma unroll
  for (int g = 0; g < COLS / 64; ++g) {
    int n = nb + (g << 6);
    unsigned int w0, w1, w2, w3;
    if constexpr (F32) {
      const float* s0 = (const float*)src + (long)(k0 + 2 * kp) * ld + n0 + n;
      const float* s1 = s0 + ld;
      float4 a = *(const float4*)s0;
      float4 b = *(const float4*)s1;
      w0 = f2bu(a.x) | ((unsigned)f2bu(b.x) << 16);
      w1 = f2bu(a.y) | ((unsigned)f2bu(b.y) << 16);
      w2 = f2bu(a.z) | ((unsigned)f2bu(b.z) << 16);
      w3 = f2bu(a.w) | ((unsigned)f2bu(b.w) << 16);
    } else {
      const unsigned short* s0 = (const unsigned short*)src + (long)(k0 + 2 * kp) * ld + n0 + n;
      const unsigned short* s1 = s0 + ld;
      ushort4 a = *(const ushort4*)s0;
      ushort4 b = *(const ushort4*)s1;
      w0 = a.x | ((unsigned)b.x << 16);
      w1 = a.y | ((unsigned)b.y << 16);
      w2 = a.z | ((unsigned)b.z << 16);
      w3 = a.w | ((unsigned)b.w << 16);
    }
    dst[(n + 0) * 20 + kp] = w0;
    dst[(n + 1) * 20 + kp] = w1;
    dst[(n + 2) * 20 + kp] = w2;
    dst[(n + 3) * 20 + kp] = w3;
  }
}

#define EQKV 0
#define EA2 1
#define EY 4
#define EG2 5
#define EG3 6
#define EG4 7
#define EWT 8
#define EBIAS 9

struct GP {
  const void* A; const void* Al;
  const void* B; const void* Bl;
  long ldA, ldB, sA, sB;
  int K;
  void* C0; void* C1; void* C2;
  long sC, ldC;
  const void* x0; const void* x1;
  const float* bias;
};

// SWZ: 0 = 3D grid (x=n,y=m,z=batch); 1 = linear 1536, XCD-affine 128x12 tiles;
//      2 = linear 512, XCD-affine 128x4 tiles.
template<int BM, int BN, int WX, int ASRC, int BMODE, int SPLIT, int EPI, int SWZ>
__global__ __launch_bounds__(256, 2) void mgemm(GP p) {
  constexpr int WY = 4 / WX;
  constexpr int TM = BM / WY, TN = BN / WX;
  constexpr int IT = TM / 16, JT = TN / 16;
  constexpr int AB = (SPLIT ? 2 : 1) * BM * 80;
  constexpr int BB = (SPLIT ? 2 : 1) * BN * 80;
  __shared__ __align__(16) char Lbuf[AB + BB];
  bf16* AsL = (bf16*)Lbuf;
  unsigned int* BsL = (unsigned int*)(Lbuf + AB);
  int t = threadIdx.x;
  int wv = t >> 6, lane = t & 63;
  int wy = wv / WX, wx = wv % WX;
  int qd = lane >> 4, lm = lane & 15;
  long bz, m0, n0;
  if constexpr (SWZ == 1) {
    int b = blockIdx.x, xcd = b & 7, s = b >> 3;
    bz = 0; m0 = (long)(xcd * 16 + s / 12) * BM; n0 = (long)(s % 12) * BN;
  } else if constexpr (SWZ == 2) {
    int b = blockIdx.x, xcd = b & 7, s = b >> 3;
    bz = 0; m0 = (long)(xcd * 16 + (s >> 2)) * BM; n0 = (long)(s & 3) * BN;
  } else {
    bz = blockIdx.z; m0 = (long)blockIdx.y * BM; n0 = (long)blockIdx.x * BN;
  }

  const void* Ap; const void* Alp = nullptr;
  if constexpr (ASRC == 0) Ap = (const bf16*)p.A + bz * p.sA;
  else Ap = p.A;
  if constexpr (SPLIT) Alp = (const bf16*)p.Al + bz * p.sA;
  const void* Bp; const void* Blp = nullptr;
  if constexpr (BMODE == 2) Bp = p.B;
  else Bp = (const bf16*)p.B + bz * p.sB;
  if constexpr (SPLIT) Blp = (const bf16*)p.Bl + bz * p.sB;

  f32x4 acc[IT][JT];
#pragma unroll
  for (int i = 0; i < IT; ++i)
#pragma unroll
    for (int j = 0; j < JT; ++j) acc[i][j] = (f32x4)0.0f;

  for (int k0 = 0; k0 < p.K; k0 += 32) {
    stageA<BM, ASRC>(Ap, p.ldA, m0, k0, AsL, t);
    if constexpr (SPLIT) stageA<BM, 0>(Alp, p.ldA, m0, k0, AsL + BM * 40, t);
    if constexpr (BMODE == 0) {
      stageA<BN, 0>(Bp, p.ldB, n0, k0, (bf16*)BsL, t);
      if constexpr (SPLIT) stageA<BN, 0>(Blp, p.ldB, n0, k0, (bf16*)BsL + BN * 40, t);
    } else {
      stageBN<BN, BMODE == 2>(Bp, p.ldB, n0, k0, BsL, t);
      if constexpr (SPLIT) stageBN<BN, false>(Blp, p.ldB, n0, k0, BsL + BN * 20, t);
    }
    __syncthreads();
    bf16x8 af[IT], afl[IT];
#pragma unroll
    for (int i = 0; i < IT; ++i) {
      int m = wy * TM + i * 16 + lm;
      af[i] = *(const bf16x8*)(AsL + m * 40 + qd * 8);
      if constexpr (SPLIT) afl[i] = *(const bf16x8*)(AsL + BM * 40 + m * 40 + qd * 8);
    }
#pragma unroll
    for (int j = 0; j < JT; ++j) {
      int n = wx * TN + j * 16 + lm;
      bf16x8 bf, bfl;
      if constexpr (BMODE == 0) {
        bf = *(const bf16x8*)((const bf16*)BsL + n * 40 + qd * 8);
        if constexpr (SPLIT) bfl = *(const bf16x8*)((const bf16*)BsL + BN * 40 + n * 40 + qd * 8);
      } else {
        bf = *(const bf16x8*)((const bf16*)(BsL + n * 20 + qd * 4));
        if constexpr (SPLIT) bfl = *(const bf16x8*)((const bf16*)(BsL + BN * 20 + n * 20 + qd * 4));
      }
#pragma unroll
      for (int i = 0; i < IT; ++i) {
        acc[i][j] = mfma16(af[i], bf, acc[i][j]);
        if constexpr (SPLIT) {
          acc[i][j] = mfma16(af[i], bfl, acc[i][j]);
          acc[i][j] = mfma16(afl[i], bf, acc[i][j]);
        }
      }
    }
    __syncthreads();
  }

  if constexpr (EPI == EA2) {
#pragma unroll
    for (int r = 0; r < 4; ++r) {
      long row = m0 + wy * TM + qd * 4 + r;
      float e[JT];
      float s = 0.f;
#pragma unroll
      for (int j = 0; j < JT; ++j) { e[j] = __expf(acc[0][j][r]); s += e[j]; }
      s += __shfl_xor(s, 1); s += __shfl_xor(s, 2);
      s += __shfl_xor(s, 4); s += __shfl_xor(s, 8);
      float inv = 1.0f / s;
#pragma unroll
      for (int j = 0; j < JT; ++j) {
        long col = n0 + j * 16 + lm;
        split_store((bf16*)p.C0, (bf16*)p.C1, bz * p.sC + row * p.ldC + col, e[j] * inv);
      }
    }
  } else {
#pragma unroll
    for (int i = 0; i < IT; ++i)
#pragma unroll
      for (int j = 0; j < JT; ++j)
#pragma unroll
        for (int r = 0; r < 4; ++r) {
          long row = m0 + wy * TM + i * 16 + qd * 4 + r;
          long col = n0 + wx * TN + j * 16 + lm;
          float v = acc[i][j][r];
          if constexpr (EPI == EQKV) {
            int part = (int)(col >> 9);
            long h = (col >> 6) & 7, d = col & 63;
            long bb = row >> 12, ii = row & 4095;
            float scv = part == 0 ? 0.125f : 1.0f;
            bf16* dst = part == 0 ? (bf16*)p.C0 : (part == 1 ? (bf16*)p.C1 : (bf16*)p.C2);
            dst[((bb * 8 + h) * 4096 + ii) * 64 + d] = (bf16)(v * scv);
          } else if constexpr (EPI == EY) {
            split_store((bf16*)p.C0, (bf16*)p.C1, bz * 65536 + row * 256 + col, v);
          } else if constexpr (EPI == EG2) {
            long ix = bz * 65536 + row * 256 + col;
            float y = (float)((const bf16*)p.x0)[ix] + (float)((const bf16*)p.x1)[ix];
            float val = (row == col ? 15.0f : 0.0f) - 7.0f * y + v;
            split_store((bf16*)p.C0, (bf16*)p.C1, ix, val);
          } else if constexpr (EPI == EG3) {
            float val = (row == col ? 13.0f : 0.0f) - v;
            split_store((bf16*)p.C0, (bf16*)p.C1, bz * 65536 + row * 256 + col, val);
          } else if constexpr (EPI == EG4) {
            split_store((bf16*)p.C0, (bf16*)p.C1, bz * 65536 + row * 256 + col, 0.25f * v);
          } else if constexpr (EPI == EWT) {
            ((bf16*)p.C0)[bz * 16384 + col * 256 + row] = (bf16)v;
          } else if constexpr (EPI == EBIAS) {
            ((float*)p.C0)[row * 512 + col] = v + p.bias[col];
          }
        }
  }
}

// ---------------- flash a3v: accumulate exp(ql k^T) v into fp32 + row sums ------
// linear grid 512, XCD-affine: same (bh,kt) K/V strip stays on one XCD.
__global__ __launch_bounds__(256, 2) void k_a3v(const bf16* __restrict__ qlh,
                                                const bf16* __restrict__ kb,
                                                const bf16* __restrict__ vb,
                                                float* __restrict__ a3vf,
                                                float* __restrict__ rs3) {
  __shared__ __align__(16) char L[38400];
  bf16* qlS = (bf16*)L;                     // [64][72]
  bf16* kS  = (bf16*)(L + 9216);            // [64][72]
  bf16* PA  = (bf16*)(L + 18432);           // [64][72]
  unsigned int* vB0 = (unsigned int*)(L + 27648);  // [64][20]
  unsigned int* vB1 = (unsigned int*)(L + 32768);  // [64][20]
  float* rsL = (float*)(L + 37888);         // [64][2]
  int b = blockIdx.x, t = threadIdx.x;
  int xcd = b & 7, s = b >> 3;
  int strip = xcd * 16 + (s >> 2);
  int qt = s & 3;
  long bz = strip >> 2;
  int kt = strip & 3;
  int wv = t >> 6, lane = t & 63, qd = lane >> 4, lm = lane & 15;
  int wy = wv >> 1, wx = wv & 1;
  const bf16* qlp = qlh + bz * 16384 + qt * 64 * 64;
#pragma unroll
  for (int c = 0; c < 2; ++c) {
    int idx = t + 256 * c;
    int r = idx >> 3, dc = (idx & 7) * 8;
    *(bf16x8*)(qlS + r * 72 + dc) = *(const bf16x8*)(qlp + r * 64 + dc);
  }
  const bf16* kb_ = kb + bz * 262144 + (long)kt * 65536;
  const bf16* vb_ = vb + bz * 262144 + (long)kt * 65536;
  f32x4 accO[2][2];
  float rsum[2][4];
#pragma unroll
  for (int i = 0; i < 2; ++i) {
#pragma unroll
    for (int j = 0; j < 2; ++j) accO[i][j] = (f32x4)0.0f;
#pragma unroll
    for (int r = 0; r < 4; ++r) rsum[i][r] = 0.f;
  }
  for (int tt = 0; tt < 16; ++tt) {
    __syncthreads();
    const bf16* ks_ = kb_ + tt * 4096;
#pragma unroll
    for (int c = 0; c < 2; ++c) {
      int idx = t + 256 * c;
      int r = idx >> 3, dc = (idx & 7) * 8;
      *(bf16x8*)(kS + r * 72 + dc) = *(const bf16x8*)(ks_ + r * 64 + dc);
    }
    const bf16* vs_ = vb_ + tt * 4096;
    stageBN<64, false>(vs_, 64, 0, 0, vB0, t);
    stageBN<64, false>(vs_, 64, 0, 32, vB1, t);
    __syncthreads();
    f32x4 s2[2][2];
#pragma unroll
    for (int i = 0; i < 2; ++i)
#pragma unroll
      for (int j = 0; j < 2; ++j) s2[i][j] = (f32x4)0.0f;
#pragma unroll
    for (int ks = 0; ks < 2; ++ks) {
      bf16x8 af[2], bfv[2];
#pragma unroll
      for (int i = 0; i < 2; ++i)
        af[i] = *(const bf16x8*)(qlS + (wy * 32 + i * 16 + lm) * 72 + ks * 32 + qd * 8);
#pragma unroll
      for (int j = 0; j < 2; ++j)
        bfv[j] = *(const bf16x8*)(kS + (wx * 32 + j * 16 + lm) * 72 + ks * 32 + qd * 8);
#pragma unroll
      for (int i = 0; i < 2; ++i)
#pragma unroll
        for (int j = 0; j < 2; ++j) s2[i][j] = mfma16(af[i], bfv[j], s2[i][j]);
    }
#pragma unroll
    for (int i = 0; i < 2; ++i)
#pragma unroll
      for (int r = 0; r < 4; ++r) {
        float e0 = __expf(s2[i][0][r]);
        float e1 = __expf(s2[i][1][r]);
        int row = wy * 32 + i * 16 + qd * 4 + r;
        PA[row * 72 + wx * 32 + 0 * 16 + lm] = (bf16)e0;
        PA[row * 72 + wx * 32 + 1 * 16 + lm] = (bf16)e1;
        float cs = e0 + e1;
        cs += __shfl_xor(cs, 1); cs += __shfl_xor(cs, 2);
        cs += __shfl_xor(cs, 4); cs += __shfl_xor(cs, 8);
        rsum[i][r] += cs;
      }
    __syncthreads();
#pragma unroll
    for (int ks = 0; ks < 2; ++ks) {
      unsigned int* vB = ks ? vB1 : vB0;
      bf16x8 af[2], bfv[2];
#pragma unroll
      for (int i = 0; i < 2; ++i)
        af[i] = *(const bf16x8*)(PA + (wy * 32 + i * 16 + lm) * 72 + ks * 32 + qd * 8);
#pragma unroll
      for (int j = 0; j < 2; ++j)
        bfv[j] = *(const bf16x8*)((const bf16*)(vB + (wx * 32 + j * 16 + lm) * 20) + qd * 8);
#pragma unroll
      for (int i = 0; i < 2; ++i)
#pragma unroll
        for (int j = 0; j < 2; ++j) accO[i][j] = mfma16(af[i], bfv[j], accO[i][j]);
    }
  }
  if (lm == 0) {
#pragma unroll
    for (int i = 0; i < 2; ++i)
#pragma unroll
      for (int r = 0; r < 4; ++r)
        rsL[(wy * 32 + i * 16 + qd * 4 + r) * 2 + wx] = rsum[i][r];
  }
  __syncthreads();
  if (t < 64) atomicAdd(&rs3[bz * 256 + qt * 64 + t], rsL[t * 2] + rsL[t * 2 + 1]);
#pragma unroll
  for (int i = 0; i < 2; ++i)
#pragma unroll
    for (int j = 0; j < 2; ++j)
#pragma unroll
      for (int r = 0; r < 4; ++r) {
        long row = bz * 256 + qt * 64 + wy * 32 + i * 16 + qd * 4 + r;
        long col = wx * 32 + j * 16 + lm;
        atomicAdd(&a3vf[row * 64 + col], accO[i][j][r]);
      }
}

__global__ void k_a3vnorm(const float* __restrict__ a3vf, const float* __restrict__ rs3,
                          bf16* __restrict__ a3vh, bf16* __restrict__ a3vl) {
  long e0 = ((long)blockIdx.x * 256 + threadIdx.x) * 4;
  float4 vv = *(const float4*)&a3vf[e0];
  float inv = 1.0f / rs3[e0 >> 6];
  split_store(a3vh, a3vl, e0 + 0, vv.x * inv);
  split_store(a3vh, a3vl, e0 + 1, vv.y * inv);
  split_store(a3vh, a3vl, e0 + 2, vv.z * inv);
  split_store(a3vh, a3vl, e0 + 3, vv.w * inv);
}

// ---------------- small kernels ----------------
__global__ void k_zero(float* a3vf, float* rs3, unsigned int* sc) {
  long i = (long)blockIdx.x * 256 + threadIdx.x;
  a3vf[i] = 0.f;
  if (i < 8192) rs3[i] = 0.f;
  if (i == 0) sc[0] = 0u;
}

__global__ void k_landmarks(const bf16* q, const bf16* k, bf16* qlh, bf16* qll,
                            bf16* klh, bf16* kll) {
  int bm = blockIdx.x;
  int bh = bm >> 8, mi = bm & 255;
  int d = threadIdx.x;
  const bf16* qp = q + ((long)bh * 4096 + mi * 16) * 64 + d;
  const bf16* kp = k + ((long)bh * 4096 + mi * 16) * 64 + d;
  float sq = 0.f, sk = 0.f;
#pragma unroll
  for (int tt = 0; tt < 16; ++tt) { sq += (float)qp[tt * 64]; sk += (float)kp[tt * 64]; }
  sq *= 0.0625f; sk *= 0.0625f;
  long o = (long)bh * 16384 + mi * 64 + d;
  split_store(qlh, qll, o, sq);
  split_store(klh, kll, o, sk);
}

__global__ __launch_bounds__(256) void k_colsum(const bf16* A2h, const bf16* A2l,
                                                unsigned int* sc) {
  int bh = blockIdx.x, j = threadIdx.x;
  const bf16* ph = A2h + (long)bh * 65536 + j;
  const bf16* pl = A2l + (long)bh * 65536 + j;
  float s = 0.f;
  for (int i = 0; i < 256; ++i) s += (float)ph[i * 256] + (float)pl[i * 256];
  __shared__ float red[256];
  red[j] = s; __syncthreads();
  for (int o = 128; o > 0; o >>= 1) {
    if (j < o) red[j] = fmaxf(red[j], red[j + o]);
    __syncthreads();
  }
  if (j == 0) atomicMax(sc, __float_as_uint(red[0]));
}

__global__ __launch_bounds__(256) void k_zinit(const bf16* A2h, const bf16* A2l,
                                               const unsigned int* sc, bf16* zh, bf16* zl) {
  __shared__ float T[64][65];
  int bh = blockIdx.z, ti = blockIdx.y, tj = blockIdx.x;
  int t = threadIdx.x;
  int c = t & 63, r0 = t >> 6;
  long base = (long)bh * 65536;
  float inv = 1.0f / __uint_as_float(sc[0]);
#pragma unroll
  for (int rr = 0; rr < 16; ++rr) {
    int r = r0 * 16 + rr;
    long idx = base + (long)(ti * 64 + r) * 256 + tj * 64 + c;
    T[r][c] = (float)A2h[idx] + (float)A2l[idx];
  }
  __syncthreads();
#pragma unroll
  for (int rr = 0; rr < 16; ++rr) {
    int jl = r0 * 16 + rr;
    float v = T[c][jl] * inv;
    long o = base + (long)(tj * 64 + jl) * 256 + ti * 64 + c;
    split_store(zh, zl, o, v);
  }
}

// fused: oh = softmax(q @ kl^T) @ W  (bf16 out), Wt [bh][64][256]
__global__ __launch_bounds__(256, 2) void k_attn1w(const bf16* qb, const bf16* klb,
                                                   const bf16* Wt, bf16* oh) {
  __shared__ __align__(16) char L[38912];
  bf16* Aq = (bf16*)L;             // [64][40]
  bf16* Bkl = (bf16*)(L + 5120);   // [256][40]
  bf16* Pl = (bf16*)L;             // [64][264] (reuse after stage-1)
  bf16* Bw = (bf16*)(L + 33792);   // [64][40]
  int t = threadIdx.x, wv = t >> 6, lane = t & 63;
  int qd = lane >> 4, lm = lane & 15;
  long bz = blockIdx.z;
  long m0 = (long)blockIdx.x * 64;
  const bf16* qA = qb + bz * (4096L * 64);
  const bf16* klA = klb + bz * (256L * 64);
  const bf16* WtA = Wt + bz * 16384;

  f32x4 a1[16];
#pragma unroll
  for (int j = 0; j < 16; ++j) a1[j] = (f32x4)0.0f;
  for (int k0 = 0; k0 < 64; k0 += 32) {
    stageA<64, 0>(qA, 64, m0, k0, Aq, t);
    stageA<256, 0>(klA, 64, 0, k0, Bkl, t);
    __syncthreads();
    bf16x8 af = *(const bf16x8*)(Aq + (wv * 16 + lm) * 40 + qd * 8);
#pragma unroll
    for (int j = 0; j < 16; ++j) {
      bf16x8 bf = *(const bf16x8*)(Bkl + (j * 16 + lm) * 40 + qd * 8);
      a1[j] = mfma16(af, bf, a1[j]);
    }
    __syncthreads();
  }
  float rs[4];
#pragma unroll
  for (int r = 0; r < 4; ++r) {
    int rowl = wv * 16 + qd * 4 + r;
    float ev[16];
    float s = 0.f;
#pragma unroll
    for (int j = 0; j < 16; ++j) { ev[j] = __expf(a1[j][r]); s += ev[j]; }
    s += __shfl_xor(s, 1); s += __shfl_xor(s, 2);
    s += __shfl_xor(s, 4); s += __shfl_xor(s, 8);
    rs[r] = s;
#pragma unroll
    for (int j = 0; j < 16; ++j) {
      float other = __shfl_xor(ev[j], 1);
      if ((lm & 1) == 0) {
        unsigned int w = f2bu(ev[j]) | ((unsigned)f2bu(other) << 16);
        *(unsigned int*)(Pl + rowl * 264 + j * 16 + lm) = w;
      }
    }
  }
  f32x4 a2[4];
#pragma unroll
  for (int j = 0; j < 4; ++j) a2[j] = (f32x4)0.0f;
  for (int k0 = 0; k0 < 256; k0 += 32) {
    stageA<64, 0>(WtA, 256, 0, k0, Bw, t);
    __syncthreads();
    bf16x8 af = *(const bf16x8*)(Pl + (wv * 16 + lm) * 264 + k0 + qd * 8);
#pragma unroll
    for (int j = 0; j < 4; ++j) {
      bf16x8 bf = *(const bf16x8*)(Bw + (j * 16 + lm) * 40 + qd * 8);
      a2[j] = mfma16(af, bf, a2[j]);
    }
    __syncthreads();
  }
#pragma unroll
  for (int j = 0; j < 4; ++j)
#pragma unroll
    for (int r = 0; r < 4; ++r) {
      long grow = m0 + wv * 16 + qd * 4 + r;
      long col = j * 16 + lm;
      oh[(bz * 4096 + grow) * 64 + col] = (bf16)(a2[j][r] / rs[r]);
    }
}

// depthwise conv residual, LDS-tiled sliding window, oh (bf16) += conv(v)
__global__ __launch_bounds__(256) void k_conv2(const bf16* __restrict__ v,
                                               const float* __restrict__ kern,
                                               bf16* __restrict__ oh) {
  __shared__ __align__(16) bf16 Vs[96 * 72];
  int bx = blockIdx.x;
  int bh = bx >> 6;
  int i0 = (bx & 63) * 64;
  int t = threadIdx.x;
  const bf16* vsrc = v + (long)bh * 262144;
#pragma unroll
  for (int c = 0; c < 3; ++c) {
    int idx = t + 256 * c;
    int r = idx >> 3, dc = (idx & 7) * 8;
    int grow = i0 + r - 16;
    bf16x8 val = (bf16x8)(bf16)0.0f;
    if (grow >= 0 && grow < 4096) val = *(const bf16x8*)(vsrc + (long)grow * 64 + dc);
    *(bf16x8*)(Vs + r * 72 + dc) = val;
  }
  __syncthreads();
  int dg = t & 15, rg = t >> 4;
  const float* kc = kern + (bh & 7) * 33;
  float acc[4][4] = {};
#pragma unroll
  for (int rr = 0; rr < 36; ++rr) {
    bf16x4 xv = *(const bf16x4*)(Vs + (rg * 4 + rr) * 72 + dg * 4);
    float x0 = (float)xv[0], x1 = (float)xv[1], x2 = (float)xv[2], x3 = (float)xv[3];
#pragma unroll
    for (int r = 0; r < 4; ++r) {
      int u = rr - r;
      if (u >= 0 && u < 33) {
        float kw = kc[u];
        acc[r][0] = fmaf(kw, x0, acc[r][0]);
        acc[r][1] = fmaf(kw, x1, acc[r][1]);
        acc[r][2] = fmaf(kw, x2, acc[r][2]);
        acc[r][3] = fmaf(kw, x3, acc[r][3]);
      }
    }
  }
  long base = ((long)bh * 4096 + i0 + rg * 4) * 64 + dg * 4;
#pragma unroll
  for (int r = 0; r < 4; ++r) {
    bf16x4 o = *(const bf16x4*)(oh + base + r * 64);
    bf16x4 w;
#pragma unroll
    for (int c = 0; c < 4; ++c) w[c] = (bf16)(acc[r][c] + (float)o[c]);
    *(bf16x4*)(oh + base + r * 64) = w;
  }
}

// ---------------- host ----------------
extern "C" void kernel_launch(void* const* d_in, const int* in_sizes, int n_in,
                              void* d_out, int out_size, void* d_ws, size_t ws_size,
                              hipStream_t stream) {
  const float* x     = (const float*)d_in[0];
  const float* w_qkv = (const float*)d_in[1];
  const float* w_out = (const float*)d_in[2];
  const float* b_out = (const float*)d_in[3];
  const float* res_k = (const float*)d_in[4];

  char* w = (char*)d_ws;
  bf16* qb  = (bf16*)(w);
  bf16* kb  = (bf16*)(w + 16777216);
  bf16* vb  = (bf16*)(w + 33554432);
  bf16* qlh = (bf16*)(w + 50331648);
  bf16* qll = (bf16*)(w + 51380224);
  bf16* klh = (bf16*)(w + 52428800);
  bf16* kll = (bf16*)(w + 53477376);
  bf16* A2h = (bf16*)(w + 54525952);
  bf16* A2l = (bf16*)(w + 58720256);
  bf16* zAh = (bf16*)(w + 62914560);
  bf16* zAl = (bf16*)(w + 67108864);
  bf16* zBh = (bf16*)(w + 71303168);
  bf16* zBl = (bf16*)(w + 75497472);
  bf16* yh  = (bf16*)(w + 79691776);
  bf16* yl  = (bf16*)(w + 83886080);
  bf16* bbh = (bf16*)(w + 88080384);
  bf16* bbl = (bf16*)(w + 92274688);
  bf16* cch = (bf16*)(w + 96468992);
  bf16* ccl = (bf16*)(w + 100663296);
  bf16* oh  = (bf16*)(w + 104857600);       // 16.8 MB bf16
  float* a3vf = (float*)(w + 121634816);    // 2 MB
  bf16* a3vh = (bf16*)(w + 123731968);
  bf16* a3vl = (bf16*)(w + 124780544);
  bf16* Wt   = (bf16*)(w + 125829120);
  float* rs3 = (float*)(w + 126877696);
  unsigned int* sc  = (unsigned int*)(w + 126910464);

  k_zero<<<2048, 256, 0, stream>>>(a3vf, rs3, sc);

  // qkv projection (fp32 in, bf16 head-layout out, q scaled), XCD-affine swizzle
  GP p{};
  p.A = x; p.ldA = 512; p.B = w_qkv; p.ldB = 1536; p.K = 512;
  p.C0 = qb; p.C1 = kb; p.C2 = vb;
  mgemm<128, 128, 2, 1, 2, 0, EQKV, 1><<<1536, 256, 0, stream>>>(p);

  k_landmarks<<<8192, 64, 0, stream>>>(qb, kb, qlh, qll, klh, kll);

  // attn2 = softmax(ql @ kl^T), split-precision
  p = GP{};
  p.A = qlh; p.Al = qll; p.ldA = 64; p.sA = 16384;
  p.B = klh; p.Bl = kll; p.ldB = 64; p.sB = 16384; p.K = 64;
  p.C0 = A2h; p.C1 = A2l; p.sC = 65536; p.ldC = 256;
  mgemm<64, 256, 1, 0, 0, 1, EA2, 0><<<dim3(1, 4, 32), 256, 0, stream>>>(p);

  k_colsum<<<32, 256, 0, stream>>>(A2h, A2l, sc);
  k_zinit<<<dim3(4, 4, 32), 256, 0, stream>>>(A2h, A2l, sc, zAh, zAl);

  // a3v = softmax(ql @ k^T) @ v  — flash accumulation + normalize
  k_a3v<<<512, 256, 0, stream>>>(qlh, kb, vb, a3vf, rs3);
  k_a3vnorm<<<512, 256, 0, stream>>>(a3vf, rs3, a3vh, a3vl);

  // Newton-Schulz pinv: iters 0-3 plain bf16 (self-correcting), iters 4-5 split
  bf16 *zch = zAh, *zcl = zAl, *znh = zBh, *znl = zBl;
  for (int it = 0; it < 6; ++it) {
    p = GP{};
    p.ldA = 256; p.sA = 65536; p.ldB = 256; p.sB = 65536; p.K = 256;
    p.A = A2h; p.Al = A2l; p.B = zch; p.Bl = zcl;
    p.C0 = yh; p.C1 = yl;
    if (it < 4) mgemm<64, 64, 2, 0, 1, 0, EY, 0><<<dim3(4, 4, 32), 256, 0, stream>>>(p);
    else        mgemm<64, 64, 2, 0, 1, 1, EY, 0><<<dim3(4, 4, 32), 256, 0, stream>>>(p);
    p.A = yh; p.Al = yl; p.B = yh; p.Bl = yl;
    p.C0 = bbh; p.C1 = bbl; p.x0 = yh; p.x1 = yl;
    if (it < 4) mgemm<64, 64, 2, 0, 1, 0, EG2, 0><<<dim3(4, 4, 32), 256, 0, stream>>>(p);
    else        mgemm<64, 64, 2, 0, 1, 1, EG2, 0><<<dim3(4, 4, 32), 256, 0, stream>>>(p);
    p.A = yh; p.Al = yl; p.B = bbh; p.Bl = bbl; p.C0 = cch; p.C1 = ccl;
    if (it < 4) mgemm<64, 64, 2, 0, 1, 0, EG3, 0><<<dim3(4, 4, 32), 256, 0, stream>>>(p);
    else        mgemm<64, 64, 2, 0, 1, 1, EG3, 0><<<dim3(4, 4, 32), 256, 0, stream>>>(p);
    p.A = zch; p.Al = zcl; p.B = cch; p.Bl = ccl; p.C0 = znh; p.C1 = znl;
    if (it < 4) mgemm<64, 64, 2, 0, 1, 0, EG4, 0><<<dim3(4, 4, 32), 256, 0, stream>>>(p);
    else        mgemm<64, 64, 2, 0, 1, 1, EG4, 0><<<dim3(4, 4, 32), 256, 0, stream>>>(p);
    bf16* tmp;
    tmp = zch; zch = znh; znh = tmp;
    tmp = zcl; zcl = znl; znl = tmp;
  }

  // Wt = (z @ a3v)^T
  p = GP{};
  p.A = zch; p.Al = zcl; p.ldA = 256; p.sA = 65536;
  p.B = a3vh; p.Bl = a3vl; p.ldB = 64; p.sB = 16384; p.K = 256;
  p.C0 = Wt;
  mgemm<64, 64, 2, 0, 1, 1, EWT, 0><<<dim3(1, 4, 32), 256, 0, stream>>>(p);

  // oh = softmax(q @ kl^T) @ W (fused), bf16 out
  k_attn1w<<<dim3(64, 1, 32), 256, 0, stream>>>(qb, klh, Wt, oh);

  // += depthwise conv residual
  k_conv2<<<2048, 256, 0, stream>>>(vb, res_k, oh);

  // out = gather(oh bf16) @ w_out + bias, XCD-affine swizzle
  p = GP{};
  p.A = oh; p.B = w_out; p.ldB = 512; p.K = 512;
  p.C0 = d_out; p.bias = b_out;
  mgemm<128, 128, 2, 3, 2, 0, EBIAS, 2><<<512, 256, 0, stream>>>(p);
}